// Round 3
// baseline (1586.890 us; speedup 1.0000x reference)
//
#include <hip/hip_runtime.h>

#define BATCH   32
#define SEQ     2048
#define IN_DIM  32
#define HID     512
#define STATE   64
#define NLAYERS 4
#define NTOK    (BATCH*SEQ)          // 65536
#define EPS     1e-5f
#define KTAN    2.8853900817779268f  // 2*log2(e)

#define F4(p)  (*reinterpret_cast<float4*>(p))
#define CF4(p) (*reinterpret_cast<const float4*>(p))
#define CF2(p) (*reinterpret_cast<const float2*>(p))

__device__ __forceinline__ float fast_exp2(float x){ return __builtin_amdgcn_exp2f(x); }
__device__ __forceinline__ float fast_rcp(float x){ return __builtin_amdgcn_rcpf(x); }

// ---------------------------------------------------------------------------
// h = x @ Win + bin.  BM=16 rows per 256-thread block, dense float4 stores.
__global__ __launch_bounds__(256) void k_input(const float* __restrict__ x,
    const float* __restrict__ Win, const float* __restrict__ bin,
    float* __restrict__ h)
{
  __shared__ float xs[16][32];
  int m0 = blockIdx.x * 16;
  int tid = threadIdx.x;
  #pragma unroll
  for (int i=0;i<2;i++){
    int idx = tid + i*256;
    xs[idx>>5][idx&31] = x[(m0 + (idx>>5))*IN_DIM + (idx&31)];
  }
  __syncthreads();
  int tx = tid & 63, ty = tid >> 6;
  int c0 = tx*4, r0 = ty*4;
  float4 bv0 = CF4(&bin[c0]);
  float4 bv1 = CF4(&bin[c0+256]);
  float4 acc[4][2];
  #pragma unroll
  for (int i=0;i<4;i++){ acc[i][0]=bv0; acc[i][1]=bv1; }
  #pragma unroll 8
  for (int k=0;k<IN_DIM;k++){
    float4 w0 = CF4(&Win[k*HID + c0]);
    float4 w1 = CF4(&Win[k*HID + c0 + 256]);
    #pragma unroll
    for (int i=0;i<4;i++){
      float xv = xs[r0+i][k];
      acc[i][0].x = fmaf(xv, w0.x, acc[i][0].x);
      acc[i][0].y = fmaf(xv, w0.y, acc[i][0].y);
      acc[i][0].z = fmaf(xv, w0.z, acc[i][0].z);
      acc[i][0].w = fmaf(xv, w0.w, acc[i][0].w);
      acc[i][1].x = fmaf(xv, w1.x, acc[i][1].x);
      acc[i][1].y = fmaf(xv, w1.y, acc[i][1].y);
      acc[i][1].z = fmaf(xv, w1.z, acc[i][1].z);
      acc[i][1].w = fmaf(xv, w1.w, acc[i][1].w);
    }
  }
  #pragma unroll
  for (int i=0;i<4;i++){
    int m = m0 + r0 + i;
    F4(&h[m*HID + c0])       = acc[i][0];
    F4(&h[m*HID + c0 + 256]) = acc[i][1];
  }
}

// ---------------------------------------------------------------------------
// Per layer precompute: A'[j][s] = g[j]*A[j][s], GA[s]=sum_j A', BA[s]=sum_j b[j]*A.
__global__ void k_prep(const float* __restrict__ A, const float* __restrict__ g,
                       const float* __restrict__ b, float* __restrict__ Ap,
                       float* __restrict__ GA, float* __restrict__ BA)
{
  int l = blockIdx.x, s = threadIdx.x;
  const float* Al = A + l*HID*STATE;
  const float* gl = g + l*HID;
  const float* bl = b + l*HID;
  float ga=0.f, ba=0.f;
  for (int j=0;j<HID;j++){
    float a  = Al[j*STATE + s];
    float ap = gl[j]*a;
    Ap[l*HID*STATE + j*STATE + s] = ap;
    ga += ap; ba += bl[j]*a;
  }
  GA[l*STATE+s]=ga; BA[l*STATE+s]=ba;
}

// ---------------------------------------------------------------------------
// Layer-0 closed-form precompute from x-side weights.
__global__ void k_prep2(const float* __restrict__ Win, const float* __restrict__ bin,
    const float* __restrict__ A0, const float* __restrict__ g0,
    float* __restrict__ M2, float* __restrict__ w1, float* __restrict__ wb,
    float* __restrict__ sc, float* __restrict__ WA1, float* __restrict__ binA)
{
  int b = blockIdx.x, tid = threadIdx.x;
  if (b == 0){
    for (int e = tid; e < 1024; e += 256){
      int a_ = e >> 5, c_ = e & 31;
      float s_ = 0.f;
      for (int j=0;j<HID;j++) s_ = fmaf(Win[a_*HID+j], Win[c_*HID+j], s_);
      M2[e] = s_;
    }
    if (tid < 32){
      float s1=0.f, s2=0.f;
      for (int j=0;j<HID;j++){
        float w = Win[tid*HID+j];
        s1 += w; s2 = fmaf(w, bin[j], s2);
      }
      w1[tid]=s1; wb[tid]=s2;
    }
    if (tid == 32){
      float sb=0.f, b2=0.f;
      for (int j=0;j<HID;j++){ float v=bin[j]; sb+=v; b2=fmaf(v,v,b2); }
      sc[0]=sb; sc[1]=b2;
    }
  } else if (b == 1){
    for (int e = tid; e < 2048; e += 256){
      int k = e >> 6, s = e & 63;
      float acc = 0.f;
      for (int j=0;j<HID;j++) acc = fmaf(Win[k*HID+j], g0[j]*A0[j*STATE+s], acc);
      WA1[e] = acc;
    }
  } else {
    if (tid < 64){
      float acc = 0.f;
      for (int j=0;j<HID;j++) acc = fmaf(bin[j], g0[j]*A0[j*STATE+tid], acc);
      binA[tid] = acc;
    }
  }
}

// ---------------------------------------------------------------------------
// U_0 directly from x, plus layer-0 LN stats.
__global__ __launch_bounds__(256) void k_u1(const float* __restrict__ x,
    const float* __restrict__ M2, const float* __restrict__ w1,
    const float* __restrict__ wb, const float* __restrict__ sc,
    const float* __restrict__ WA1, const float* __restrict__ binA,
    const float* __restrict__ GA, const float* __restrict__ BA,
    float* __restrict__ U, float2* __restrict__ stats)
{
  int rw = threadIdx.x >> 6;
  int lane = threadIdx.x & 63;
  int m = blockIdx.x*4 + rw;
  __shared__ float xs[4][32];
  if (lane < 32) xs[rw][lane] = x[m*IN_DIM + lane];
  __syncthreads();
  float qp = 0.f, sp = 0.f;
  if (lane < 32){
    float p = 0.f;
    #pragma unroll 8
    for (int j=0;j<32;j++) p = fmaf(M2[lane*32+j], xs[rw][j], p);
    float xv = xs[rw][lane];
    qp = xv * fmaf(2.f, wb[lane], p);
    sp = xv * w1[lane];
  }
  #pragma unroll
  for (int off=16; off; off>>=1){ qp += __shfl_xor(qp, off); sp += __shfl_xor(sp, off); }
  qp = __shfl(qp, 0); sp = __shfl(sp, 0);
  float mu  = (sp + sc[0]) * (1.f/HID);
  float msq = (qp + sc[1]) * (1.f/HID);
  float rs  = rsqrtf(fmaxf(msq - mu*mu, 0.f) + EPS);
  if (lane == 0) stats[m] = make_float2(mu, rs);
  float u = binA[lane];
  #pragma unroll 8
  for (int k=0;k<32;k++) u = fmaf(xs[rw][k], WA1[k*STATE+lane], u);
  U[m*STATE+lane] = KTAN*(rs*(u - mu*GA[lane]) + BA[lane]);
}

// ---------------------------------------------------------------------------
// Sequential recurrence. 32 blocks x 64 threads, thread (b,s) owns one chain.
__global__ __launch_bounds__(64) void k_scan(const float* __restrict__ U,
                                             float* __restrict__ H)
{
  int b = blockIdx.x;
  int s = threadIdx.x;
  const float* Up = U + b*SEQ*STATE + s;
  float* Hp = H + b*SEQ*STATE + s;
  float g = 0.f;
  float cur[16], nxt[16];
  #pragma unroll
  for (int i=0;i<16;i++) cur[i] = Up[i*STATE];
  for (int t0=0; t0<SEQ; t0+=16){
    bool has_next = (t0+16 < SEQ);
    if (has_next){
      #pragma unroll
      for (int i=0;i<16;i++) nxt[i] = Up[(t0+16+i)*STATE];
    }
    #pragma unroll
    for (int i=0;i<16;i++){
      float e = fast_exp2(cur[i] + g);
      float r = fast_rcp(1.f + e);
      Hp[(t0+i)*STATE] = fmaf(-2.f, r, 1.f);
      g = fmaf(-2.f*KTAN, r, KTAN);
    }
    if (has_next){
      #pragma unroll
      for (int i=0;i<16;i++) cur[i] = nxt[i];
    }
  }
}

// ---------------------------------------------------------------------------
// Fused layer epilogue + next-layer U GEMM.
//  h[m][:] += H[m]@C^T + LN(h)[m][:]*D           (Y epilogue, in place)
//  stats_out[m] = (mu, rstd) of new h row
//  if has_next: U[m][s] = KTAN*(rs*(h_new[m]@A' - mu*GA[s]) + BA[s])
// BM=32 rows/block, 256 threads (tx=tid&15 -> 4 cols, ty=tid>>4 -> 2 rows).
// Per 64-col chunk: Y-GEMM -> h_new chunk to global + transposed LDS ->
// partial U accumulation (linear in h_new; LN affine applied at the end).
__global__ __launch_bounds__(256) void k_fuse(
    float* __restrict__ h, const float* __restrict__ Hg,
    const float* __restrict__ C, const float* __restrict__ Dl,
    const float* __restrict__ gl, const float* __restrict__ bl,
    const float2* __restrict__ stats_in, float2* __restrict__ stats_out,
    const float* __restrict__ Ap, const float* __restrict__ GA,
    const float* __restrict__ BA, float* __restrict__ U, int has_next)
{
  __shared__ float HshT[STATE][33];   // [s][m-local]   8.25 KB
  __shared__ float CshT[STATE][65];   // [s][j-chunk]  16.25 KB
  __shared__ float As  [64][65];      // [j-chunk][s]  16.25 KB
  __shared__ float hT  [64][33];      // [j-chunk][m]   8.25 KB
  int m0 = blockIdx.x * 32;
  int tid = threadIdx.x;
  int tx = tid & 15, ty = tid >> 4;   // tx: 4-col group, ty: 2-row group

  // stage H tile transposed (32 rows x 64 s)
  #pragma unroll
  for (int i=0;i<2;i++){
    int idx = tid + i*256;            // 0..511
    int mr = idx >> 4;                // 0..31
    int s4 = idx & 15;
    float4 v = CF4(&Hg[(m0+mr)*STATE + s4*4]);
    HshT[s4*4+0][mr] = v.x;
    HshT[s4*4+1][mr] = v.y;
    HshT[s4*4+2][mr] = v.z;
    HshT[s4*4+3][mr] = v.w;
  }
  float2 st_in[2];
  st_in[0] = stats_in[m0 + ty*2];
  st_in[1] = stats_in[m0 + ty*2 + 1];
  float sum[2] = {0.f,0.f}, sq[2] = {0.f,0.f};
  float uacc[2][4] = {};

  for (int jc=0; jc<HID; jc+=64){
    // stage C chunk transposed: rows jc..jc+63 -> CshT[s][jr]
    #pragma unroll
    for (int i=0;i<4;i++){
      int idx = tid + i*256;          // 0..1023
      int jr = idx >> 4;              // 0..63
      int s4 = idx & 15;
      float4 v = CF4(&C[(jc+jr)*STATE + s4*4]);
      CshT[s4*4+0][jr] = v.x;
      CshT[s4*4+1][jr] = v.y;
      CshT[s4*4+2][jr] = v.z;
      CshT[s4*4+3][jr] = v.w;
    }
    if (has_next){
      #pragma unroll
      for (int i=0;i<4;i++){
        int idx = tid + i*256;
        int jr = idx >> 4;
        int s4 = idx & 15;
        F4(&As[jr][s4*4]) = CF4(&Ap[(jc+jr)*STATE + s4*4]);
      }
    }
    __syncthreads();

    // phase 1: Y chunk = H @ C^T  (2 rows x 4 cols per thread)
    float acc[2][4] = {};
    #pragma unroll 16
    for (int s=0;s<STATE;s++){
      float2 a = CF2(&HshT[s][ty*2]);
      float4 b = CF4(&CshT[s][tx*4]);
      acc[0][0] = fmaf(a.x, b.x, acc[0][0]);
      acc[0][1] = fmaf(a.x, b.y, acc[0][1]);
      acc[0][2] = fmaf(a.x, b.z, acc[0][2]);
      acc[0][3] = fmaf(a.x, b.w, acc[0][3]);
      acc[1][0] = fmaf(a.y, b.x, acc[1][0]);
      acc[1][1] = fmaf(a.y, b.y, acc[1][1]);
      acc[1][2] = fmaf(a.y, b.z, acc[1][2]);
      acc[1][3] = fmaf(a.y, b.w, acc[1][3]);
    }

    // epilogue for this chunk: residual + D*LN(h_old); write global + hT
    int j0 = jc + tx*4;
    float4 g4 = CF4(&gl[j0]);
    float4 b4 = CF4(&bl[j0]);
    float4 d4 = CF4(&Dl[j0]);
    #pragma unroll
    for (int r=0;r<2;r++){
      int m = m0 + ty*2 + r;
      float4 hv = CF4(&h[m*HID + j0]);
      float mu = st_in[r].x, rs = st_in[r].y;
      float4 o;
      o.x = hv.x + acc[r][0] + fmaf((hv.x - mu)*rs, g4.x, b4.x)*d4.x;
      o.y = hv.y + acc[r][1] + fmaf((hv.y - mu)*rs, g4.y, b4.y)*d4.y;
      o.z = hv.z + acc[r][2] + fmaf((hv.z - mu)*rs, g4.z, b4.z)*d4.z;
      o.w = hv.w + acc[r][3] + fmaf((hv.w - mu)*rs, g4.w, b4.w)*d4.w;
      F4(&h[m*HID + j0]) = o;
      sum[r] += (o.x+o.y)+(o.z+o.w);
      sq[r]  += (o.x*o.x+o.y*o.y)+(o.z*o.z+o.w*o.w);
      int mr = ty*2 + r;
      hT[tx*4+0][mr] = o.x;
      hT[tx*4+1][mr] = o.y;
      hT[tx*4+2][mr] = o.z;
      hT[tx*4+3][mr] = o.w;
    }
    __syncthreads();

    // phase 3: partial U accumulation over this chunk's 64 j values
    if (has_next){
      #pragma unroll 16
      for (int j=0;j<64;j++){
        float a0 = hT[j][ty*2];
        float a1 = hT[j][ty*2+1];
        float4 b = CF4(&As[j][tx*4]);
        uacc[0][0] = fmaf(a0, b.x, uacc[0][0]);
        uacc[0][1] = fmaf(a0, b.y, uacc[0][1]);
        uacc[0][2] = fmaf(a0, b.z, uacc[0][2]);
        uacc[0][3] = fmaf(a0, b.w, uacc[0][3]);
        uacc[1][0] = fmaf(a1, b.x, uacc[1][0]);
        uacc[1][1] = fmaf(a1, b.y, uacc[1][1]);
        uacc[1][2] = fmaf(a1, b.z, uacc[1][2]);
        uacc[1][3] = fmaf(a1, b.w, uacc[1][3]);
      }
    }
    __syncthreads();
  }

  // stats: reduce across the 16 tx lanes (butterfly -> all lanes hold result)
  float mu2[2], rs2[2];
  #pragma unroll
  for (int r=0;r<2;r++){
    float s_ = sum[r], q = sq[r];
    #pragma unroll
    for (int off=1; off<16; off<<=1){
      s_ += __shfl_xor(s_, off);
      q  += __shfl_xor(q,  off);
    }
    float mu  = s_*(1.f/HID);
    float var = q*(1.f/HID) - mu*mu;
    float rs  = rsqrtf(fmaxf(var,0.f)+EPS);
    mu2[r]=mu; rs2[r]=rs;
    if (tx==0) stats_out[m0 + ty*2 + r] = make_float2(mu, rs);
  }
  if (has_next){
    int s0 = tx*4;
    float4 ga = CF4(&GA[s0]);
    float4 ba = CF4(&BA[s0]);
    #pragma unroll
    for (int r=0;r<2;r++){
      int m = m0 + ty*2 + r;
      float4 o;
      o.x = KTAN*(rs2[r]*(uacc[r][0] - mu2[r]*ga.x) + ba.x);
      o.y = KTAN*(rs2[r]*(uacc[r][1] - mu2[r]*ga.y) + ba.y);
      o.z = KTAN*(rs2[r]*(uacc[r][2] - mu2[r]*ga.z) + ba.z);
      o.w = KTAN*(rs2[r]*(uacc[r][3] - mu2[r]*ga.w) + ba.w);
      F4(&U[m*STATE + s0]) = o;
    }
  }
}

// ---------------------------------------------------------------------------
// Final LN (stats precomputed) on last token + MLP head.
__global__ __launch_bounds__(256) void k_head(const float* __restrict__ h,
   const float2* __restrict__ stats, const float* __restrict__ ng, const float* __restrict__ nb,
   const float* __restrict__ W1, const float* __restrict__ b1,
   const float* __restrict__ W2, const float* __restrict__ b2,
   float* __restrict__ out)
{
  int bb = blockIdx.x;
  int m = bb*SEQ + (SEQ-1);
  int tid = threadIdx.x;
  __shared__ float xs[HID];
  __shared__ float red[8];
  float2 st = stats[m];
  #pragma unroll
  for (int i=0;i<2;i++){
    int j = tid + i*256;
    float v = h[m*HID + j];
    xs[j] = fmaf((v - st.x)*st.y, ng[j], nb[j]);
  }
  __syncthreads();
  float acc = b1[tid];
  #pragma unroll 8
  for (int j=0;j<HID;j++) acc = fmaf(xs[j], W1[j*(HID/2) + tid], acc);
  float ge = 0.5f*acc*(1.f + erff(acc*0.70710678118654752f));
  float p0 = ge*W2[tid*2+0];
  float p1 = ge*W2[tid*2+1];
  #pragma unroll
  for (int off=32; off; off>>=1){ p0 += __shfl_down(p0, off); p1 += __shfl_down(p1, off); }
  int wid = tid>>6;
  if ((tid&63)==0){ red[wid*2]=p0; red[wid*2+1]=p1; }
  __syncthreads();
  if (tid==0){
    float o0=b2[0], o1=b2[1];
    #pragma unroll
    for (int w=0;w<4;w++){ o0+=red[w*2]; o1+=red[w*2+1]; }
    out[bb*2+0]=o0; out[bb*2+1]=o1;
  }
}

// ---------------------------------------------------------------------------
extern "C" void kernel_launch(void* const* d_in, const int* in_sizes, int n_in,
                              void* d_out, int out_size, void* d_ws, size_t ws_size,
                              hipStream_t stream)
{
  (void)in_sizes; (void)n_in; (void)out_size; (void)ws_size;
  const float* x   = (const float*)d_in[0];
  const float* Win = (const float*)d_in[1];
  const float* bin = (const float*)d_in[2];
  const float* A   = (const float*)d_in[3];
  const float* C   = (const float*)d_in[4];
  const float* Dv  = (const float*)d_in[5];
  const float* lng = (const float*)d_in[6];
  const float* lnb = (const float*)d_in[7];
  const float* ng  = (const float*)d_in[8];
  const float* nb  = (const float*)d_in[9];
  const float* W1  = (const float*)d_in[10];
  const float* b1  = (const float*)d_in[11];
  const float* W2  = (const float*)d_in[12];
  const float* b2  = (const float*)d_in[13];
  float* out = (float*)d_out;
  char* ws = (char*)d_ws;
  float*  hbuf = (float*)(ws + 0);                       // 134,217,728
  float*  Ubuf = (float*)(ws + (size_t)134217728);       //  16,777,216
  float*  Hbuf = (float*)(ws + (size_t)150994944);       //  16,777,216
  float2* st0  = (float2*)(ws + (size_t)167772160);      //     524,288
  float2* st1  = (float2*)(ws + (size_t)168296448);      //     524,288
  float*  Ap   = (float*)(ws + (size_t)168820736);       //     524,288
  float*  GAb  = (float*)(ws + (size_t)169345024);       //       1,024
  float*  BAb  = (float*)(ws + (size_t)169346048);       //       1,024
  float*  M2b  = (float*)(ws + (size_t)169347072);       //       4,096
  float*  w1b  = (float*)(ws + (size_t)169351168);       //         128
  float*  wbb  = (float*)(ws + (size_t)169351296);       //         128
  float*  scb  = (float*)(ws + (size_t)169351424);       //           8
  float*  WA1b = (float*)(ws + (size_t)169351432);       //       8,192
  float*  binAb= (float*)(ws + (size_t)169359624);       //         256

  hipLaunchKernelGGL(k_prep,  dim3(NLAYERS), dim3(64),  0, stream, A, lng, lnb, Ap, GAb, BAb);
  hipLaunchKernelGGL(k_prep2, dim3(3),       dim3(256), 0, stream, Win, bin, A, lng,
      M2b, w1b, wbb, scb, WA1b, binAb);
  hipLaunchKernelGGL(k_input, dim3(NTOK/16), dim3(256), 0, stream, x, Win, bin, hbuf);
  hipLaunchKernelGGL(k_u1,    dim3(NTOK/4),  dim3(256), 0, stream, x,
      M2b, w1b, wbb, scb, WA1b, binAb, GAb, BAb, Ubuf, st0);
  float2* scur = st0; float2* snxt = st1;
  for (int l=0; l<NLAYERS; ++l){
    int has_next = (l < NLAYERS-1) ? 1 : 0;
    int ln = has_next ? (l+1) : 0;   // safe pointer when unused
    hipLaunchKernelGGL(k_scan, dim3(BATCH),   dim3(64),  0, stream, Ubuf, Hbuf);
    hipLaunchKernelGGL(k_fuse, dim3(NTOK/32), dim3(256), 0, stream,
        hbuf, Hbuf, C + l*HID*STATE, Dv + l*HID, lng + l*HID, lnb + l*HID,
        scur, snxt, Ap + ln*HID*STATE, GAb + ln*STATE, BAb + ln*STATE, Ubuf, has_next);
    float2* t = scur; scur = snxt; snxt = t;
  }
  hipLaunchKernelGGL(k_head, dim3(BATCH), dim3(256), 0, stream,
      hbuf, scur, ng, nb, W1, b1, W2, b2, out);
}

// Round 4
// 1100.074 us; speedup vs baseline: 1.4425x; 1.4425x over previous
//
#include <hip/hip_runtime.h>

#define BATCH   32
#define SEQ     2048
#define IN_DIM  32
#define HID     512
#define STATE   64
#define NLAYERS 4
#define NTOK    (BATCH*SEQ)          // 65536
#define EPS     1e-5f
#define KTAN    2.8853900817779268f  // 2*log2(e)

#define F4(p)  (*reinterpret_cast<float4*>(p))
#define CF4(p) (*reinterpret_cast<const float4*>(p))

__device__ __forceinline__ float fast_exp2(float x){ return __builtin_amdgcn_exp2f(x); }
__device__ __forceinline__ float fast_rcp(float x){ return __builtin_amdgcn_rcpf(x); }

// ---------------------------------------------------------------------------
// h = x @ Win + bin.  BM=16 rows per 256-thread block, dense float4 stores.
__global__ __launch_bounds__(256) void k_input(const float* __restrict__ x,
    const float* __restrict__ Win, const float* __restrict__ bin,
    float* __restrict__ h)
{
  __shared__ float xs[16][32];
  int m0 = blockIdx.x * 16;
  int tid = threadIdx.x;
  #pragma unroll
  for (int i=0;i<2;i++){
    int idx = tid + i*256;
    xs[idx>>5][idx&31] = x[(m0 + (idx>>5))*IN_DIM + (idx&31)];
  }
  __syncthreads();
  int tx = tid & 63, ty = tid >> 6;
  int c0 = tx*4, r0 = ty*4;
  float4 bv0 = CF4(&bin[c0]);
  float4 bv1 = CF4(&bin[c0+256]);
  float4 acc[4][2];
  #pragma unroll
  for (int i=0;i<4;i++){ acc[i][0]=bv0; acc[i][1]=bv1; }
  #pragma unroll 8
  for (int k=0;k<IN_DIM;k++){
    float4 w0 = CF4(&Win[k*HID + c0]);
    float4 w1 = CF4(&Win[k*HID + c0 + 256]);
    #pragma unroll
    for (int i=0;i<4;i++){
      float xv = xs[r0+i][k];
      acc[i][0].x = fmaf(xv, w0.x, acc[i][0].x);
      acc[i][0].y = fmaf(xv, w0.y, acc[i][0].y);
      acc[i][0].z = fmaf(xv, w0.z, acc[i][0].z);
      acc[i][0].w = fmaf(xv, w0.w, acc[i][0].w);
      acc[i][1].x = fmaf(xv, w1.x, acc[i][1].x);
      acc[i][1].y = fmaf(xv, w1.y, acc[i][1].y);
      acc[i][1].z = fmaf(xv, w1.z, acc[i][1].z);
      acc[i][1].w = fmaf(xv, w1.w, acc[i][1].w);
    }
  }
  #pragma unroll
  for (int i=0;i<4;i++){
    int m = m0 + r0 + i;
    F4(&h[m*HID + c0])       = acc[i][0];
    F4(&h[m*HID + c0 + 256]) = acc[i][1];
  }
}

// ---------------------------------------------------------------------------
__global__ void k_prep(const float* __restrict__ A, const float* __restrict__ g,
                       const float* __restrict__ b, float* __restrict__ Ap,
                       float* __restrict__ GA, float* __restrict__ BA)
{
  int l = blockIdx.x, s = threadIdx.x;
  const float* Al = A + l*HID*STATE;
  const float* gl = g + l*HID;
  const float* bl = b + l*HID;
  float ga=0.f, ba=0.f;
  for (int j=0;j<HID;j++){
    float a  = Al[j*STATE + s];
    float ap = gl[j]*a;
    Ap[l*HID*STATE + j*STATE + s] = ap;
    ga += ap; ba += bl[j]*a;
  }
  GA[l*STATE+s]=ga; BA[l*STATE+s]=ba;
}

// ---------------------------------------------------------------------------
__global__ void k_prep2(const float* __restrict__ Win, const float* __restrict__ bin,
    const float* __restrict__ A0, const float* __restrict__ g0,
    float* __restrict__ M2, float* __restrict__ w1, float* __restrict__ wb,
    float* __restrict__ sc, float* __restrict__ WA1, float* __restrict__ binA)
{
  int b = blockIdx.x, tid = threadIdx.x;
  if (b == 0){
    for (int e = tid; e < 1024; e += 256){
      int a_ = e >> 5, c_ = e & 31;
      float s_ = 0.f;
      for (int j=0;j<HID;j++) s_ = fmaf(Win[a_*HID+j], Win[c_*HID+j], s_);
      M2[e] = s_;
    }
    if (tid < 32){
      float s1=0.f, s2=0.f;
      for (int j=0;j<HID;j++){
        float w = Win[tid*HID+j];
        s1 += w; s2 = fmaf(w, bin[j], s2);
      }
      w1[tid]=s1; wb[tid]=s2;
    }
    if (tid == 32){
      float sb=0.f, b2=0.f;
      for (int j=0;j<HID;j++){ float v=bin[j]; sb+=v; b2=fmaf(v,v,b2); }
      sc[0]=sb; sc[1]=b2;
    }
  } else if (b == 1){
    for (int e = tid; e < 2048; e += 256){
      int k = e >> 6, s = e & 63;
      float acc = 0.f;
      for (int j=0;j<HID;j++) acc = fmaf(Win[k*HID+j], g0[j]*A0[j*STATE+s], acc);
      WA1[e] = acc;
    }
  } else {
    if (tid < 64){
      float acc = 0.f;
      for (int j=0;j<HID;j++) acc = fmaf(bin[j], g0[j]*A0[j*STATE+tid], acc);
      binA[tid] = acc;
    }
  }
}

// ---------------------------------------------------------------------------
// U_0 directly from x, plus layer-0 LN stats. U pre-scaled: KTAN*x' + KTAN.
__global__ __launch_bounds__(256) void k_u1(const float* __restrict__ x,
    const float* __restrict__ M2, const float* __restrict__ w1,
    const float* __restrict__ wb, const float* __restrict__ sc,
    const float* __restrict__ WA1, const float* __restrict__ binA,
    const float* __restrict__ GA, const float* __restrict__ BA,
    float* __restrict__ U, float2* __restrict__ stats)
{
  int rw = threadIdx.x >> 6;
  int lane = threadIdx.x & 63;
  int m = blockIdx.x*4 + rw;
  __shared__ float xs[4][32];
  if (lane < 32) xs[rw][lane] = x[m*IN_DIM + lane];
  __syncthreads();
  float qp = 0.f, sp = 0.f;
  if (lane < 32){
    float p = 0.f;
    #pragma unroll 8
    for (int j=0;j<32;j++) p = fmaf(M2[lane*32+j], xs[rw][j], p);
    float xv = xs[rw][lane];
    qp = xv * fmaf(2.f, wb[lane], p);
    sp = xv * w1[lane];
  }
  #pragma unroll
  for (int off=16; off; off>>=1){ qp += __shfl_xor(qp, off); sp += __shfl_xor(sp, off); }
  qp = __shfl(qp, 0); sp = __shfl(sp, 0);
  float mu  = (sp + sc[0]) * (1.f/HID);
  float msq = (qp + sc[1]) * (1.f/HID);
  float rs  = rsqrtf(fmaxf(msq - mu*mu, 0.f) + EPS);
  if (lane == 0) stats[m] = make_float2(mu, rs);
  float u = binA[lane];
  #pragma unroll 8
  for (int k=0;k<32;k++) u = fmaf(xs[rw][k], WA1[k*STATE+lane], u);
  U[m*STATE+lane] = fmaf(KTAN, rs*(u - mu*GA[lane]) + BA[lane], KTAN);
}

// ---------------------------------------------------------------------------
// U[m][s] = KTAN*( rstd*(h@A' - mu*GA) + BA ) + KTAN   (layers 1..3)
// BM=128, BK=32, 256 thr, 8m x 4n. LDS staged via register 4x4 transpose
// into stride-132 rows (132 = 4*33, odd f4-stride -> even bank-start spread).
__global__ __launch_bounds__(256) void k_ugemm(const float* __restrict__ h,
    const float2* __restrict__ stats, const float* __restrict__ Ap,
    const float* __restrict__ GA, const float* __restrict__ BA,
    float* __restrict__ U)
{
  __shared__ float hsT[32][132];   // [k][m]  16.9 KB
  __shared__ float Bs[32][68];     // [k][n]   8.7 KB
  int m0 = blockIdx.x * 128;
  int tid = threadIdx.x;
  int tx = tid & 15, ty = tid >> 4;
  int kg = tid & 7,  mg = tid >> 3;     // kg: 8 k-groups of 4, mg: 32 m-groups of 4
  float acc[8][4] = {};
  for (int kc=0; kc<HID; kc+=32){
    {
      const float* hp = &h[(size_t)(m0 + mg*4)*HID + kc + kg*4];
      float4 v0 = CF4(hp);
      float4 v1 = CF4(hp + HID);
      float4 v2 = CF4(hp + 2*HID);
      float4 v3 = CF4(hp + 3*HID);
      F4(&hsT[kg*4+0][mg*4]) = make_float4(v0.x,v1.x,v2.x,v3.x);
      F4(&hsT[kg*4+1][mg*4]) = make_float4(v0.y,v1.y,v2.y,v3.y);
      F4(&hsT[kg*4+2][mg*4]) = make_float4(v0.z,v1.z,v2.z,v3.z);
      F4(&hsT[kg*4+3][mg*4]) = make_float4(v0.w,v1.w,v2.w,v3.w);
    }
    #pragma unroll
    for (int i=0;i<2;i++){
      int idx = tid + i*256;
      int kr = idx >> 4;
      int c4 = idx & 15;
      F4(&Bs[kr][c4*4]) = CF4(&Ap[(kc+kr)*STATE + c4*4]);
    }
    __syncthreads();
    #pragma unroll 8
    for (int kk=0;kk<32;kk++){
      float4 a0 = CF4(&hsT[kk][ty*8]);
      float4 a1 = CF4(&hsT[kk][ty*8+4]);
      float4 bv = CF4(&Bs[kk][tx*4]);
      float am[8] = {a0.x,a0.y,a0.z,a0.w,a1.x,a1.y,a1.z,a1.w};
      #pragma unroll
      for (int i=0;i<8;i++){
        acc[i][0] = fmaf(am[i], bv.x, acc[i][0]);
        acc[i][1] = fmaf(am[i], bv.y, acc[i][1]);
        acc[i][2] = fmaf(am[i], bv.z, acc[i][2]);
        acc[i][3] = fmaf(am[i], bv.w, acc[i][3]);
      }
    }
    __syncthreads();
  }
  int c0 = tx*4;
  float4 ga = CF4(&GA[c0]);
  float4 ba = CF4(&BA[c0]);
  #pragma unroll
  for (int i=0;i<8;i++){
    int m = m0 + ty*8 + i;
    float2 st = stats[m];
    float4 o;
    o.x = fmaf(KTAN, st.y*(acc[i][0] - st.x*ga.x) + ba.x, KTAN);
    o.y = fmaf(KTAN, st.y*(acc[i][1] - st.x*ga.y) + ba.y, KTAN);
    o.z = fmaf(KTAN, st.y*(acc[i][2] - st.x*ga.z) + ba.z, KTAN);
    o.w = fmaf(KTAN, st.y*(acc[i][3] - st.x*ga.w) + ba.w, KTAN);
    F4(&U[(size_t)m*STATE + c0]) = o;
  }
}

// ---------------------------------------------------------------------------
// Producer/consumer scan. 32 blocks x 256 threads. Wave 0 runs the 64 chains
// (4-op dependent step: fma -> exp2 -> add -> rcp; U pre-scaled & +KTAN so
// exponent = fma(-2K, r, u)); waves 1-3 double-buffer U in and flush H out.
__global__ __launch_bounds__(256) void k_scan(const float* __restrict__ U,
                                              float* __restrict__ H)
{
  __shared__ float Ul[2][64][64];    // 32 KB
  __shared__ float Hl[2][64][64];    // 32 KB
  int b = blockIdx.x, tid = threadIdx.x;
  int lane = tid & 63, wv = tid >> 6;
  const float* Ub = U + (size_t)b*SEQ*STATE;
  float* Hb = H + (size_t)b*SEQ*STATE;
  const int NC = SEQ/64;             // 32 chunks
  #pragma unroll
  for (int i=0;i<4;i++){
    int idx = tid + i*256;
    F4(&Ul[0][0][0] + idx*4) = CF4(Ub + idx*4);
  }
  __syncthreads();
  float r = 0.5f;                    // r = 1/(1+e^{2x}); tanh(0) -> r=0.5
  for (int c=0; c<NC; ++c){
    int cb = c & 1;
    if (wv == 0){
      #pragma unroll 8
      for (int t=0;t<64;t++){
        float u = Ul[cb][t][lane];
        float e = fast_exp2(fmaf(-2.f*KTAN, r, u));
        r = fast_rcp(1.f + e);
        Hl[cb][t][lane] = fmaf(-2.f, r, 1.f);
      }
    } else {
      int li = tid - 64;             // 0..191
      float4 ld[6];
      if (c+1 < NC){
        const float* src = Ub + (size_t)(c+1)*4096;
        #pragma unroll
        for (int i=0;i<6;i++){
          int idx = li + i*192;
          if (idx < 1024) ld[i] = CF4(src + idx*4);
        }
      }
      if (c > 0){
        float* dst = Hb + (size_t)(c-1)*4096;
        const float* sl = &Hl[cb^1][0][0];
        #pragma unroll
        for (int i=0;i<6;i++){
          int idx = li + i*192;
          if (idx < 1024) F4(dst + idx*4) = CF4(sl + idx*4);
        }
      }
      if (c+1 < NC){
        float* dl = &Ul[cb^1][0][0];
        #pragma unroll
        for (int i=0;i<6;i++){
          int idx = li + i*192;
          if (idx < 1024) F4(dl + idx*4) = ld[i];
        }
      }
    }
    __syncthreads();
  }
  float* dst = Hb + (size_t)(NC-1)*4096;
  const float* sl = &Hl[(NC-1)&1][0][0];
  for (int idx = tid; idx < 1024; idx += 256)
    F4(dst + idx*4) = CF4(sl + idx*4);
}

// ---------------------------------------------------------------------------
// Y epilogue, in place: h += H@C^T + LN(h)*D; emits next-layer row stats.
// BM=128, 256 thr, 8m x 4j. LDS via register transpose; strides 132/68.
__global__ __launch_bounds__(256) void k_yep2(
    float* __restrict__ h, const float* __restrict__ Hg,
    const float* __restrict__ C, const float* __restrict__ Dl,
    const float* __restrict__ gl, const float* __restrict__ bl,
    const float2* __restrict__ stats_in, float2* __restrict__ stats_out)
{
  __shared__ float HshT[STATE][132];  // [s][m0..127]  33.8 KB
  __shared__ float CshT[STATE][68];   // [s][j-chunk]  17.4 KB
  int m0 = blockIdx.x * 128;
  int tid = threadIdx.x;
  int tx = tid & 15, ty = tid >> 4;   // tx: j-group, ty: 8-row group
  int sg = tid & 15, mgg = tid >> 4;  // staging roles
  #pragma unroll
  for (int p=0;p<2;p++){
    const float* hp = &Hg[(size_t)(m0 + p*64 + mgg*4)*STATE + sg*4];
    float4 v0 = CF4(hp);
    float4 v1 = CF4(hp + STATE);
    float4 v2 = CF4(hp + 2*STATE);
    float4 v3 = CF4(hp + 3*STATE);
    int cb = p*64 + mgg*4;
    F4(&HshT[sg*4+0][cb]) = make_float4(v0.x,v1.x,v2.x,v3.x);
    F4(&HshT[sg*4+1][cb]) = make_float4(v0.y,v1.y,v2.y,v3.y);
    F4(&HshT[sg*4+2][cb]) = make_float4(v0.z,v1.z,v2.z,v3.z);
    F4(&HshT[sg*4+3][cb]) = make_float4(v0.w,v1.w,v2.w,v3.w);
  }
  float2 st[8];
  #pragma unroll
  for (int mi=0;mi<8;mi++) st[mi] = stats_in[m0 + ty*8 + mi];
  float sum[8] = {}, sq[8] = {};
  for (int jc=0; jc<HID; jc+=64){
    {
      const float* cp = &C[(size_t)(jc + mgg*4)*STATE + sg*4];
      float4 v0 = CF4(cp);
      float4 v1 = CF4(cp + STATE);
      float4 v2 = CF4(cp + 2*STATE);
      float4 v3 = CF4(cp + 3*STATE);
      F4(&CshT[sg*4+0][mgg*4]) = make_float4(v0.x,v1.x,v2.x,v3.x);
      F4(&CshT[sg*4+1][mgg*4]) = make_float4(v0.y,v1.y,v2.y,v3.y);
      F4(&CshT[sg*4+2][mgg*4]) = make_float4(v0.z,v1.z,v2.z,v3.z);
      F4(&CshT[sg*4+3][mgg*4]) = make_float4(v0.w,v1.w,v2.w,v3.w);
    }
    __syncthreads();
    float acc[8][4] = {};
    #pragma unroll 8
    for (int s=0;s<STATE;s++){
      float4 a0 = CF4(&HshT[s][ty*8]);
      float4 a1 = CF4(&HshT[s][ty*8+4]);
      float4 bv = CF4(&CshT[s][tx*4]);
      float am[8] = {a0.x,a0.y,a0.z,a0.w,a1.x,a1.y,a1.z,a1.w};
      #pragma unroll
      for (int i=0;i<8;i++){
        acc[i][0] = fmaf(am[i], bv.x, acc[i][0]);
        acc[i][1] = fmaf(am[i], bv.y, acc[i][1]);
        acc[i][2] = fmaf(am[i], bv.z, acc[i][2]);
        acc[i][3] = fmaf(am[i], bv.w, acc[i][3]);
      }
    }
    int j0 = jc + tx*4;
    float4 g4 = CF4(&gl[j0]);
    float4 b4 = CF4(&bl[j0]);
    float4 d4 = CF4(&Dl[j0]);
    #pragma unroll
    for (int mi=0;mi<8;mi++){
      int m = m0 + ty*8 + mi;
      float4 hv = CF4(&h[(size_t)m*HID + j0]);
      float mu = st[mi].x, rs = st[mi].y;
      float4 o;
      o.x = hv.x + acc[mi][0] + fmaf((hv.x - mu)*rs, g4.x, b4.x)*d4.x;
      o.y = hv.y + acc[mi][1] + fmaf((hv.y - mu)*rs, g4.y, b4.y)*d4.y;
      o.z = hv.z + acc[mi][2] + fmaf((hv.z - mu)*rs, g4.z, b4.z)*d4.z;
      o.w = hv.w + acc[mi][3] + fmaf((hv.w - mu)*rs, g4.w, b4.w)*d4.w;
      F4(&h[(size_t)m*HID + j0]) = o;
      sum[mi] += (o.x+o.y)+(o.z+o.w);
      sq[mi]  += (o.x*o.x+o.y*o.y)+(o.z*o.z+o.w*o.w);
    }
    __syncthreads();
  }
  #pragma unroll
  for (int mi=0;mi<8;mi++){
    float s_ = sum[mi], q = sq[mi];
    #pragma unroll
    for (int off=1; off<16; off<<=1){
      s_ += __shfl_xor(s_, off);
      q  += __shfl_xor(q,  off);
    }
    if (tx==0){
      float mu  = s_*(1.f/HID);
      float var = q*(1.f/HID) - mu*mu;
      stats_out[m0 + ty*8 + mi] = make_float2(mu, rsqrtf(fmaxf(var,0.f)+EPS));
    }
  }
}

// ---------------------------------------------------------------------------
__global__ __launch_bounds__(256) void k_head(const float* __restrict__ h,
   const float2* __restrict__ stats, const float* __restrict__ ng, const float* __restrict__ nb,
   const float* __restrict__ W1, const float* __restrict__ b1,
   const float* __restrict__ W2, const float* __restrict__ b2,
   float* __restrict__ out)
{
  int bb = blockIdx.x;
  int m = bb*SEQ + (SEQ-1);
  int tid = threadIdx.x;
  __shared__ float xs[HID];
  __shared__ float red[8];
  float2 st = stats[m];
  #pragma unroll
  for (int i=0;i<2;i++){
    int j = tid + i*256;
    float v = h[(size_t)m*HID + j];
    xs[j] = fmaf((v - st.x)*st.y, ng[j], nb[j]);
  }
  __syncthreads();
  float acc = b1[tid];
  #pragma unroll 8
  for (int j=0;j<HID;j++) acc = fmaf(xs[j], W1[j*(HID/2) + tid], acc);
  float ge = 0.5f*acc*(1.f + erff(acc*0.70710678118654752f));
  float p0 = ge*W2[tid*2+0];
  float p1 = ge*W2[tid*2+1];
  #pragma unroll
  for (int off=32; off; off>>=1){ p0 += __shfl_down(p0, off); p1 += __shfl_down(p1, off); }
  int wid = tid>>6;
  if ((tid&63)==0){ red[wid*2]=p0; red[wid*2+1]=p1; }
  __syncthreads();
  if (tid==0){
    float o0=b2[0], o1=b2[1];
    #pragma unroll
    for (int w=0;w<4;w++){ o0+=red[w*2]; o1+=red[w*2+1]; }
    out[bb*2+0]=o0; out[bb*2+1]=o1;
  }
}

// ---------------------------------------------------------------------------
extern "C" void kernel_launch(void* const* d_in, const int* in_sizes, int n_in,
                              void* d_out, int out_size, void* d_ws, size_t ws_size,
                              hipStream_t stream)
{
  (void)in_sizes; (void)n_in; (void)out_size; (void)ws_size;
  const float* x   = (const float*)d_in[0];
  const float* Win = (const float*)d_in[1];
  const float* bin = (const float*)d_in[2];
  const float* A   = (const float*)d_in[3];
  const float* C   = (const float*)d_in[4];
  const float* Dv  = (const float*)d_in[5];
  const float* lng = (const float*)d_in[6];
  const float* lnb = (const float*)d_in[7];
  const float* ng  = (const float*)d_in[8];
  const float* nb  = (const float*)d_in[9];
  const float* W1  = (const float*)d_in[10];
  const float* b1  = (const float*)d_in[11];
  const float* W2  = (const float*)d_in[12];
  const float* b2  = (const float*)d_in[13];
  float* out = (float*)d_out;
  char* ws = (char*)d_ws;
  float*  hbuf = (float*)(ws + 0);                       // 134,217,728
  float*  Ubuf = (float*)(ws + (size_t)134217728);       //  16,777,216
  float*  Hbuf = (float*)(ws + (size_t)150994944);       //  16,777,216
  float2* st0  = (float2*)(ws + (size_t)167772160);      //     524,288
  float2* st1  = (float2*)(ws + (size_t)168296448);      //     524,288
  float*  Ap   = (float*)(ws + (size_t)168820736);       //     524,288
  float*  GAb  = (float*)(ws + (size_t)169345024);       //       1,024
  float*  BAb  = (float*)(ws + (size_t)169346048);       //       1,024
  float*  M2b  = (float*)(ws + (size_t)169347072);       //       4,096
  float*  w1b  = (float*)(ws + (size_t)169351168);       //         128
  float*  wbb  = (float*)(ws + (size_t)169351296);       //         128
  float*  scb  = (float*)(ws + (size_t)169351424);       //           8
  float*  WA1b = (float*)(ws + (size_t)169351432);       //       8,192
  float*  binAb= (float*)(ws + (size_t)169359624);       //         256

  hipLaunchKernelGGL(k_prep,  dim3(NLAYERS), dim3(64),  0, stream, A, lng, lnb, Ap, GAb, BAb);
  hipLaunchKernelGGL(k_prep2, dim3(3),       dim3(256), 0, stream, Win, bin, A, lng,
      M2b, w1b, wbb, scb, WA1b, binAb);
  hipLaunchKernelGGL(k_input, dim3(NTOK/16), dim3(256), 0, stream, x, Win, bin, hbuf);
  hipLaunchKernelGGL(k_u1,    dim3(NTOK/4),  dim3(256), 0, stream, x,
      M2b, w1b, wbb, scb, WA1b, binAb, GAb, BAb, Ubuf, st0);
  float2* scur = st0; float2* snxt = st1;
  for (int l=0; l<NLAYERS; ++l){
    if (l > 0){
      hipLaunchKernelGGL(k_ugemm, dim3(NTOK/128), dim3(256), 0, stream,
          hbuf, scur, Ap + l*HID*STATE, GAb + l*STATE, BAb + l*STATE, Ubuf);
    }
    hipLaunchKernelGGL(k_scan,  dim3(BATCH),    dim3(256), 0, stream, Ubuf, Hbuf);
    hipLaunchKernelGGL(k_yep2,  dim3(NTOK/128), dim3(256), 0, stream,
        hbuf, Hbuf, C + l*HID*STATE, Dv + l*HID, lng + l*HID, lnb + l*HID, scur, snxt);
    float2* t = scur; scur = snxt; snxt = t;
  }
  hipLaunchKernelGGL(k_head, dim3(BATCH), dim3(256), 0, stream,
      hbuf, scur, ng, nb, W1, b1, W2, b2, out);
}

// Round 5
// 958.923 us; speedup vs baseline: 1.6549x; 1.1472x over previous
//
#include <hip/hip_runtime.h>

#define BATCH   32
#define SEQ     2048
#define IN_DIM  32
#define HID     512
#define STATE   64
#define NLAYERS 4
#define NTOK    (BATCH*SEQ)          // 65536
#define EPS     1e-5f
#define KTAN    2.8853900817779268f  // 2*log2(e)

#define F4(p)  (*reinterpret_cast<float4*>(p))
#define CF4(p) (*reinterpret_cast<const float4*>(p))

__device__ __forceinline__ float fast_exp2(float x){ return __builtin_amdgcn_exp2f(x); }
__device__ __forceinline__ float fast_rcp(float x){ return __builtin_amdgcn_rcpf(x); }

// ---------------------------------------------------------------------------
// All precompute in one launch, 37 blocks x 256 threads, 4x128 K-split + LDS
// reduce everywhere.
//  blocks 0..3   : layer l=blk:  Ap = g*A, GA = sum_j Ap, BA = sum_j b*A
//  blocks 4..35  : WA1[k][s] = sum_j Win[k][j] * g0[j]*A0[j][s]   (k = blk-4)
//  block  36     : binA[s]   = sum_j bin[j]  * g0[j]*A0[j][s]
__global__ __launch_bounds__(256) void k_prep(
    const float* __restrict__ A, const float* __restrict__ g,
    const float* __restrict__ b, const float* __restrict__ Win,
    const float* __restrict__ bin, float* __restrict__ Ap,
    float* __restrict__ GA, float* __restrict__ BA,
    float* __restrict__ WA1, float* __restrict__ binA)
{
  __shared__ float red[4][64], red2[4][64];
  int tid = threadIdx.x;
  int s = tid & 63, part = tid >> 6;
  int blk = blockIdx.x;
  if (blk < NLAYERS){
    int l = blk;
    const float* Al = A + l*HID*STATE;
    const float* gl = g + l*HID;
    const float* bl = b + l*HID;
    float ga=0.f, ba=0.f;
    for (int j=part*128; j<(part+1)*128; ++j){
      float a  = Al[j*STATE+s];
      float ap = gl[j]*a;
      Ap[l*HID*STATE + j*STATE + s] = ap;
      ga += ap; ba = fmaf(bl[j], a, ba);
    }
    red[part][s]=ga; red2[part][s]=ba;
    __syncthreads();
    if (tid < 64){
      GA[l*STATE+s] = red[0][s]+red[1][s]+red[2][s]+red[3][s];
      BA[l*STATE+s] = red2[0][s]+red2[1][s]+red2[2][s]+red2[3][s];
    }
  } else {
    int k = blk - NLAYERS;            // 0..32; 32 => binA
    const float* w = (k < 32) ? (Win + k*HID) : bin;
    float acc = 0.f;
    for (int j=part*128; j<(part+1)*128; ++j)
      acc = fmaf(w[j], g[j]*A[j*STATE+s], acc);   // layer-0 slices of g, A
    red[part][s] = acc;
    __syncthreads();
    if (tid < 64){
      float v = red[0][s]+red[1][s]+red[2][s]+red[3][s];
      if (k < 32) WA1[k*STATE+s] = v; else binA[s] = v;
    }
  }
}

// ---------------------------------------------------------------------------
// Fused input: h = x@Win + bin; layer-0 LN stats straight from registers
// (each wave owns 4 complete rows); U_0 from xs via WA1/binA closed form.
// U pre-scaled: KTAN*xn' + KTAN.
__global__ __launch_bounds__(256) void k_input(const float* __restrict__ x,
    const float* __restrict__ Win, const float* __restrict__ bin,
    const float* __restrict__ WA1, const float* __restrict__ binA,
    const float* __restrict__ GA0, const float* __restrict__ BA0,
    float* __restrict__ h, float* __restrict__ U, float2* __restrict__ stats)
{
  __shared__ float xs[16][32];
  int m0 = blockIdx.x * 16;
  int tid = threadIdx.x;
  #pragma unroll
  for (int i=0;i<2;i++){
    int idx = tid + i*256;
    xs[idx>>5][idx&31] = x[(m0 + (idx>>5))*IN_DIM + (idx&31)];
  }
  __syncthreads();
  int lane = tid & 63, wv = tid >> 6;
  int c0 = lane*4, r0 = wv*4;
  float4 bv0 = CF4(&bin[c0]);
  float4 bv1 = CF4(&bin[c0+256]);
  float4 acc[4][2];
  #pragma unroll
  for (int i=0;i<4;i++){ acc[i][0]=bv0; acc[i][1]=bv1; }
  #pragma unroll 8
  for (int k=0;k<IN_DIM;k++){
    float4 w0 = CF4(&Win[k*HID + c0]);
    float4 w1 = CF4(&Win[k*HID + c0 + 256]);
    #pragma unroll
    for (int i=0;i<4;i++){
      float xv = xs[r0+i][k];
      acc[i][0].x = fmaf(xv, w0.x, acc[i][0].x);
      acc[i][0].y = fmaf(xv, w0.y, acc[i][0].y);
      acc[i][0].z = fmaf(xv, w0.z, acc[i][0].z);
      acc[i][0].w = fmaf(xv, w0.w, acc[i][0].w);
      acc[i][1].x = fmaf(xv, w1.x, acc[i][1].x);
      acc[i][1].y = fmaf(xv, w1.y, acc[i][1].y);
      acc[i][1].z = fmaf(xv, w1.z, acc[i][1].z);
      acc[i][1].w = fmaf(xv, w1.w, acc[i][1].w);
    }
  }
  #pragma unroll
  for (int i=0;i<4;i++){
    int m = m0 + r0 + i;
    F4(&h[(size_t)m*HID + c0])       = acc[i][0];
    F4(&h[(size_t)m*HID + c0 + 256]) = acc[i][1];
  }
  // layer-0 stats + U0, one row at a time (wave-local)
  #pragma unroll
  for (int i=0;i<4;i++){
    int m = m0 + r0 + i;
    float s_ = (acc[i][0].x+acc[i][0].y)+(acc[i][0].z+acc[i][0].w)
             + (acc[i][1].x+acc[i][1].y)+(acc[i][1].z+acc[i][1].w);
    float q  = (acc[i][0].x*acc[i][0].x + acc[i][0].y*acc[i][0].y)
             + (acc[i][0].z*acc[i][0].z + acc[i][0].w*acc[i][0].w)
             + (acc[i][1].x*acc[i][1].x + acc[i][1].y*acc[i][1].y)
             + (acc[i][1].z*acc[i][1].z + acc[i][1].w*acc[i][1].w);
    #pragma unroll
    for (int off=1; off<64; off<<=1){
      s_ += __shfl_xor(s_, off);
      q  += __shfl_xor(q,  off);
    }
    float mu  = s_*(1.f/HID);
    float var = q*(1.f/HID) - mu*mu;
    float rs  = rsqrtf(fmaxf(var,0.f)+EPS);
    if (lane == 0) stats[m] = make_float2(mu, rs);
    float u = binA[lane];
    #pragma unroll 8
    for (int k=0;k<IN_DIM;k++) u = fmaf(xs[r0+i][k], WA1[k*STATE+lane], u);
    U[(size_t)m*STATE+lane] = fmaf(KTAN, rs*(u - mu*GA0[lane]) + BA0[lane], KTAN);
  }
}

// ---------------------------------------------------------------------------
// U[m][s] = KTAN*( rstd*(h@A' - mu*GA) + BA ) + KTAN   (layers 1..3)
// BM=128, BK=32, 256 thr, 8m x 4n. LDS staged via register 4x4 transpose
// into stride-132 rows.
__global__ __launch_bounds__(256) void k_ugemm(const float* __restrict__ h,
    const float2* __restrict__ stats, const float* __restrict__ Ap,
    const float* __restrict__ GA, const float* __restrict__ BA,
    float* __restrict__ U)
{
  __shared__ float hsT[32][132];   // [k][m]  16.9 KB
  __shared__ float Bs[32][68];     // [k][n]   8.7 KB
  int m0 = blockIdx.x * 128;
  int tid = threadIdx.x;
  int tx = tid & 15, ty = tid >> 4;
  int kg = tid & 7,  mg = tid >> 3;
  float acc[8][4] = {};
  for (int kc=0; kc<HID; kc+=32){
    {
      const float* hp = &h[(size_t)(m0 + mg*4)*HID + kc + kg*4];
      float4 v0 = CF4(hp);
      float4 v1 = CF4(hp + HID);
      float4 v2 = CF4(hp + 2*HID);
      float4 v3 = CF4(hp + 3*HID);
      F4(&hsT[kg*4+0][mg*4]) = make_float4(v0.x,v1.x,v2.x,v3.x);
      F4(&hsT[kg*4+1][mg*4]) = make_float4(v0.y,v1.y,v2.y,v3.y);
      F4(&hsT[kg*4+2][mg*4]) = make_float4(v0.z,v1.z,v2.z,v3.z);
      F4(&hsT[kg*4+3][mg*4]) = make_float4(v0.w,v1.w,v2.w,v3.w);
    }
    #pragma unroll
    for (int i=0;i<2;i++){
      int idx = tid + i*256;
      int kr = idx >> 4;
      int c4 = idx & 15;
      F4(&Bs[kr][c4*4]) = CF4(&Ap[(kc+kr)*STATE + c4*4]);
    }
    __syncthreads();
    #pragma unroll 8
    for (int kk=0;kk<32;kk++){
      float4 a0 = CF4(&hsT[kk][ty*8]);
      float4 a1 = CF4(&hsT[kk][ty*8+4]);
      float4 bv = CF4(&Bs[kk][tx*4]);
      float am[8] = {a0.x,a0.y,a0.z,a0.w,a1.x,a1.y,a1.z,a1.w};
      #pragma unroll
      for (int i=0;i<8;i++){
        acc[i][0] = fmaf(am[i], bv.x, acc[i][0]);
        acc[i][1] = fmaf(am[i], bv.y, acc[i][1]);
        acc[i][2] = fmaf(am[i], bv.z, acc[i][2]);
        acc[i][3] = fmaf(am[i], bv.w, acc[i][3]);
      }
    }
    __syncthreads();
  }
  int c0 = tx*4;
  float4 ga = CF4(&GA[c0]);
  float4 ba = CF4(&BA[c0]);
  #pragma unroll
  for (int i=0;i<8;i++){
    int m = m0 + ty*8 + i;
    float2 st = stats[m];
    float4 o;
    o.x = fmaf(KTAN, st.y*(acc[i][0] - st.x*ga.x) + ba.x, KTAN);
    o.y = fmaf(KTAN, st.y*(acc[i][1] - st.x*ga.y) + ba.y, KTAN);
    o.z = fmaf(KTAN, st.y*(acc[i][2] - st.x*ga.z) + ba.z, KTAN);
    o.w = fmaf(KTAN, st.y*(acc[i][3] - st.x*ga.w) + ba.w, KTAN);
    F4(&U[(size_t)m*STATE + c0]) = o;
  }
}

// ---------------------------------------------------------------------------
// Producer/consumer scan. 32 blocks x 256 threads. Wave 0 runs the 64 chains
// (4-op dependent step); waves 1-3 double-buffer U in and flush H out.
__global__ __launch_bounds__(256) void k_scan(const float* __restrict__ U,
                                              float* __restrict__ H)
{
  __shared__ float Ul[2][64][64];    // 32 KB
  __shared__ float Hl[2][64][64];    // 32 KB
  int b = blockIdx.x, tid = threadIdx.x;
  int lane = tid & 63, wv = tid >> 6;
  const float* Ub = U + (size_t)b*SEQ*STATE;
  float* Hb = H + (size_t)b*SEQ*STATE;
  const int NC = SEQ/64;             // 32 chunks
  #pragma unroll
  for (int i=0;i<4;i++){
    int idx = tid + i*256;
    F4(&Ul[0][0][0] + idx*4) = CF4(Ub + idx*4);
  }
  __syncthreads();
  float r = 0.5f;
  for (int c=0; c<NC; ++c){
    int cb = c & 1;
    if (wv == 0){
      #pragma unroll 8
      for (int t=0;t<64;t++){
        float u = Ul[cb][t][lane];
        float e = fast_exp2(fmaf(-2.f*KTAN, r, u));
        r = fast_rcp(1.f + e);
        Hl[cb][t][lane] = fmaf(-2.f, r, 1.f);
      }
    } else {
      int li = tid - 64;             // 0..191
      float4 ld[6];
      if (c+1 < NC){
        const float* src = Ub + (size_t)(c+1)*4096;
        #pragma unroll
        for (int i=0;i<6;i++){
          int idx = li + i*192;
          if (idx < 1024) ld[i] = CF4(src + idx*4);
        }
      }
      if (c > 0){
        float* dst = Hb + (size_t)(c-1)*4096;
        const float* sl = &Hl[cb^1][0][0];
        #pragma unroll
        for (int i=0;i<6;i++){
          int idx = li + i*192;
          if (idx < 1024) F4(dst + idx*4) = CF4(sl + idx*4);
        }
      }
      if (c+1 < NC){
        float* dl = &Ul[cb^1][0][0];
        #pragma unroll
        for (int i=0;i<6;i++){
          int idx = li + i*192;
          if (idx < 1024) F4(dl + idx*4) = ld[i];
        }
      }
    }
    __syncthreads();
  }
  float* dst = Hb + (size_t)(NC-1)*4096;
  const float* sl = &Hl[(NC-1)&1][0][0];
  for (int idx = tid; idx < 1024; idx += 256)
    F4(dst + idx*4) = CF4(sl + idx*4);
}

// ---------------------------------------------------------------------------
// Y epilogue, in place: h += H@C^T + LN(h)*D; emits next-layer row stats.
// BM=128, 256 thr, 8m x 4j. LDS via register transpose; strides 132/68.
__global__ __launch_bounds__(256) void k_yep2(
    float* __restrict__ h, const float* __restrict__ Hg,
    const float* __restrict__ C, const float* __restrict__ Dl,
    const float* __restrict__ gl, const float* __restrict__ bl,
    const float2* __restrict__ stats_in, float2* __restrict__ stats_out)
{
  __shared__ float HshT[STATE][132];  // [s][m0..127]  33.8 KB
  __shared__ float CshT[STATE][68];   // [s][j-chunk]  17.4 KB
  int m0 = blockIdx.x * 128;
  int tid = threadIdx.x;
  int tx = tid & 15, ty = tid >> 4;
  int sg = tid & 15, mgg = tid >> 4;
  #pragma unroll
  for (int p=0;p<2;p++){
    const float* hp = &Hg[(size_t)(m0 + p*64 + mgg*4)*STATE + sg*4];
    float4 v0 = CF4(hp);
    float4 v1 = CF4(hp + STATE);
    float4 v2 = CF4(hp + 2*STATE);
    float4 v3 = CF4(hp + 3*STATE);
    int cb = p*64 + mgg*4;
    F4(&HshT[sg*4+0][cb]) = make_float4(v0.x,v1.x,v2.x,v3.x);
    F4(&HshT[sg*4+1][cb]) = make_float4(v0.y,v1.y,v2.y,v3.y);
    F4(&HshT[sg*4+2][cb]) = make_float4(v0.z,v1.z,v2.z,v3.z);
    F4(&HshT[sg*4+3][cb]) = make_float4(v0.w,v1.w,v2.w,v3.w);
  }
  float2 st[8];
  #pragma unroll
  for (int mi=0;mi<8;mi++) st[mi] = stats_in[m0 + ty*8 + mi];
  float sum[8] = {}, sq[8] = {};
  for (int jc=0; jc<HID; jc+=64){
    {
      const float* cp = &C[(size_t)(jc + mgg*4)*STATE + sg*4];
      float4 v0 = CF4(cp);
      float4 v1 = CF4(cp + STATE);
      float4 v2 = CF4(cp + 2*STATE);
      float4 v3 = CF4(cp + 3*STATE);
      F4(&CshT[sg*4+0][mgg*4]) = make_float4(v0.x,v1.x,v2.x,v3.x);
      F4(&CshT[sg*4+1][mgg*4]) = make_float4(v0.y,v1.y,v2.y,v3.y);
      F4(&CshT[sg*4+2][mgg*4]) = make_float4(v0.z,v1.z,v2.z,v3.z);
      F4(&CshT[sg*4+3][mgg*4]) = make_float4(v0.w,v1.w,v2.w,v3.w);
    }
    __syncthreads();
    float acc[8][4] = {};
    #pragma unroll 8
    for (int s=0;s<STATE;s++){
      float4 a0 = CF4(&HshT[s][ty*8]);
      float4 a1 = CF4(&HshT[s][ty*8+4]);
      float4 bv = CF4(&CshT[s][tx*4]);
      float am[8] = {a0.x,a0.y,a0.z,a0.w,a1.x,a1.y,a1.z,a1.w};
      #pragma unroll
      for (int i=0;i<8;i++){
        acc[i][0] = fmaf(am[i], bv.x, acc[i][0]);
        acc[i][1] = fmaf(am[i], bv.y, acc[i][1]);
        acc[i][2] = fmaf(am[i], bv.z, acc[i][2]);
        acc[i][3] = fmaf(am[i], bv.w, acc[i][3]);
      }
    }
    int j0 = jc + tx*4;
    float4 g4 = CF4(&gl[j0]);
    float4 b4 = CF4(&bl[j0]);
    float4 d4 = CF4(&Dl[j0]);
    #pragma unroll
    for (int mi=0;mi<8;mi++){
      int m = m0 + ty*8 + mi;
      float4 hv = CF4(&h[(size_t)m*HID + j0]);
      float mu = st[mi].x, rs = st[mi].y;
      float4 o;
      o.x = hv.x + acc[mi][0] + fmaf((hv.x - mu)*rs, g4.x, b4.x)*d4.x;
      o.y = hv.y + acc[mi][1] + fmaf((hv.y - mu)*rs, g4.y, b4.y)*d4.y;
      o.z = hv.z + acc[mi][2] + fmaf((hv.z - mu)*rs, g4.z, b4.z)*d4.z;
      o.w = hv.w + acc[mi][3] + fmaf((hv.w - mu)*rs, g4.w, b4.w)*d4.w;
      F4(&h[(size_t)m*HID + j0]) = o;
      sum[mi] += (o.x+o.y)+(o.z+o.w);
      sq[mi]  += (o.x*o.x+o.y*o.y)+(o.z*o.z+o.w*o.w);
    }
    __syncthreads();
  }
  #pragma unroll
  for (int mi=0;mi<8;mi++){
    float s_ = sum[mi], q = sq[mi];
    #pragma unroll
    for (int off=1; off<16; off<<=1){
      s_ += __shfl_xor(s_, off);
      q  += __shfl_xor(q,  off);
    }
    if (tx==0){
      float mu  = s_*(1.f/HID);
      float var = q*(1.f/HID) - mu*mu;
      stats_out[m0 + ty*8 + mi] = make_float2(mu, rsqrtf(fmaxf(var,0.f)+EPS));
    }
  }
}

// ---------------------------------------------------------------------------
__global__ __launch_bounds__(256) void k_head(const float* __restrict__ h,
   const float2* __restrict__ stats, const float* __restrict__ ng, const float* __restrict__ nb,
   const float* __restrict__ W1, const float* __restrict__ b1,
   const float* __restrict__ W2, const float* __restrict__ b2,
   float* __restrict__ out)
{
  int bb = blockIdx.x;
  int m = bb*SEQ + (SEQ-1);
  int tid = threadIdx.x;
  __shared__ float xs[HID];
  __shared__ float red[8];
  float2 st = stats[m];
  #pragma unroll
  for (int i=0;i<2;i++){
    int j = tid + i*256;
    float v = h[(size_t)m*HID + j];
    xs[j] = fmaf((v - st.x)*st.y, ng[j], nb[j]);
  }
  __syncthreads();
  float acc = b1[tid];
  #pragma unroll 8
  for (int j=0;j<HID;j++) acc = fmaf(xs[j], W1[j*(HID/2) + tid], acc);
  float ge = 0.5f*acc*(1.f + erff(acc*0.70710678118654752f));
  float p0 = ge*W2[tid*2+0];
  float p1 = ge*W2[tid*2+1];
  #pragma unroll
  for (int off=32; off; off>>=1){ p0 += __shfl_down(p0, off); p1 += __shfl_down(p1, off); }
  int wid = tid>>6;
  if ((tid&63)==0){ red[wid*2]=p0; red[wid*2+1]=p1; }
  __syncthreads();
  if (tid==0){
    float o0=b2[0], o1=b2[1];
    #pragma unroll
    for (int w=0;w<4;w++){ o0+=red[w*2]; o1+=red[w*2+1]; }
    out[bb*2+0]=o0; out[bb*2+1]=o1;
  }
}

// ---------------------------------------------------------------------------
extern "C" void kernel_launch(void* const* d_in, const int* in_sizes, int n_in,
                              void* d_out, int out_size, void* d_ws, size_t ws_size,
                              hipStream_t stream)
{
  (void)in_sizes; (void)n_in; (void)out_size; (void)ws_size;
  const float* x   = (const float*)d_in[0];
  const float* Win = (const float*)d_in[1];
  const float* bin = (const float*)d_in[2];
  const float* A   = (const float*)d_in[3];
  const float* C   = (const float*)d_in[4];
  const float* Dv  = (const float*)d_in[5];
  const float* lng = (const float*)d_in[6];
  const float* lnb = (const float*)d_in[7];
  const float* ng  = (const float*)d_in[8];
  const float* nb  = (const float*)d_in[9];
  const float* W1  = (const float*)d_in[10];
  const float* b1  = (const float*)d_in[11];
  const float* W2  = (const float*)d_in[12];
  const float* b2  = (const float*)d_in[13];
  float* out = (float*)d_out;
  char* ws = (char*)d_ws;
  float*  hbuf = (float*)(ws + 0);                       // 134,217,728
  float*  Ubuf = (float*)(ws + (size_t)134217728);       //  16,777,216
  float*  Hbuf = (float*)(ws + (size_t)150994944);       //  16,777,216
  float2* st0  = (float2*)(ws + (size_t)167772160);      //     524,288
  float2* st1  = (float2*)(ws + (size_t)168296448);      //     524,288
  float*  Ap   = (float*)(ws + (size_t)168820736);       //     524,288
  float*  GAb  = (float*)(ws + (size_t)169345024);       //       1,024
  float*  BAb  = (float*)(ws + (size_t)169346048);       //       1,024
  float*  WA1b = (float*)(ws + (size_t)169351432);       //       8,192
  float*  binAb= (float*)(ws + (size_t)169359624);       //         256

  hipLaunchKernelGGL(k_prep,  dim3(NLAYERS+33), dim3(256), 0, stream,
      A, lng, lnb, Win, bin, Ap, GAb, BAb, WA1b, binAb);
  hipLaunchKernelGGL(k_input, dim3(NTOK/16), dim3(256), 0, stream,
      x, Win, bin, WA1b, binAb, GAb, BAb, hbuf, Ubuf, st0);
  float2* scur = st0; float2* snxt = st1;
  for (int l=0; l<NLAYERS; ++l){
    if (l > 0){
      hipLaunchKernelGGL(k_ugemm, dim3(NTOK/128), dim3(256), 0, stream,
          hbuf, scur, Ap + l*HID*STATE, GAb + l*STATE, BAb + l*STATE, Ubuf);
    }
    hipLaunchKernelGGL(k_scan,  dim3(BATCH),    dim3(256), 0, stream, Ubuf, Hbuf);
    hipLaunchKernelGGL(k_yep2,  dim3(NTOK/128), dim3(256), 0, stream,
        hbuf, Hbuf, C + l*HID*STATE, Dv + l*HID, lng + l*HID, lnb + l*HID, scur, snxt);
    float2* t = scur; scur = snxt; snxt = t;
  }
  hipLaunchKernelGGL(k_head, dim3(BATCH), dim3(256), 0, stream,
      hbuf, scur, ng, nb, W1, b1, W2, b2, out);
}

// Round 6
// 788.694 us; speedup vs baseline: 2.0120x; 1.2158x over previous
//
#include <hip/hip_runtime.h>

#define BATCH   32
#define SEQ     2048
#define IN_DIM  32
#define HID     512
#define STATE   64
#define NLAYERS 4
#define NTOK    (BATCH*SEQ)          // 65536
#define EPS     1e-5f
#define KTAN    2.8853900817779268f  // 2*log2(e)

#define F4(p)  (*reinterpret_cast<float4*>(p))
#define CF4(p) (*reinterpret_cast<const float4*>(p))

__device__ __forceinline__ float fast_exp2(float x){ return __builtin_amdgcn_exp2f(x); }
__device__ __forceinline__ float fast_rcp(float x){ return __builtin_amdgcn_rcpf(x); }

// ---------------------------------------------------------------------------
// All precompute in one launch, 37 blocks x 256 threads.
__global__ __launch_bounds__(256) void k_prep(
    const float* __restrict__ A, const float* __restrict__ g,
    const float* __restrict__ b, const float* __restrict__ Win,
    const float* __restrict__ bin, float* __restrict__ Ap,
    float* __restrict__ GA, float* __restrict__ BA,
    float* __restrict__ WA1, float* __restrict__ binA)
{
  __shared__ float red[4][64], red2[4][64];
  int tid = threadIdx.x;
  int s = tid & 63, part = tid >> 6;
  int blk = blockIdx.x;
  if (blk < NLAYERS){
    int l = blk;
    const float* Al = A + l*HID*STATE;
    const float* gl = g + l*HID;
    const float* bl = b + l*HID;
    float ga=0.f, ba=0.f;
    for (int j=part*128; j<(part+1)*128; ++j){
      float a  = Al[j*STATE+s];
      float ap = gl[j]*a;
      Ap[l*HID*STATE + j*STATE + s] = ap;
      ga += ap; ba = fmaf(bl[j], a, ba);
    }
    red[part][s]=ga; red2[part][s]=ba;
    __syncthreads();
    if (tid < 64){
      GA[l*STATE+s] = red[0][s]+red[1][s]+red[2][s]+red[3][s];
      BA[l*STATE+s] = red2[0][s]+red2[1][s]+red2[2][s]+red2[3][s];
    }
  } else {
    int k = blk - NLAYERS;            // 0..32; 32 => binA
    const float* w = (k < 32) ? (Win + k*HID) : bin;
    float acc = 0.f;
    for (int j=part*128; j<(part+1)*128; ++j)
      acc = fmaf(w[j], g[j]*A[j*STATE+s], acc);
    red[part][s] = acc;
    __syncthreads();
    if (tid < 64){
      float v = red[0][s]+red[1][s]+red[2][s]+red[3][s];
      if (k < 32) WA1[k*STATE+s] = v; else binA[s] = v;
    }
  }
}

// ---------------------------------------------------------------------------
// Fused input: h = x@Win + bin; layer-0 LN stats from registers; U_0 closed form.
__global__ __launch_bounds__(256) void k_input(const float* __restrict__ x,
    const float* __restrict__ Win, const float* __restrict__ bin,
    const float* __restrict__ WA1, const float* __restrict__ binA,
    const float* __restrict__ GA0, const float* __restrict__ BA0,
    float* __restrict__ h, float* __restrict__ U, float2* __restrict__ stats)
{
  __shared__ float xs[16][32];
  int m0 = blockIdx.x * 16;
  int tid = threadIdx.x;
  #pragma unroll
  for (int i=0;i<2;i++){
    int idx = tid + i*256;
    xs[idx>>5][idx&31] = x[(m0 + (idx>>5))*IN_DIM + (idx&31)];
  }
  __syncthreads();
  int lane = tid & 63, wv = tid >> 6;
  int c0 = lane*4, r0 = wv*4;
  float4 bv0 = CF4(&bin[c0]);
  float4 bv1 = CF4(&bin[c0+256]);
  float4 acc[4][2];
  #pragma unroll
  for (int i=0;i<4;i++){ acc[i][0]=bv0; acc[i][1]=bv1; }
  #pragma unroll 8
  for (int k=0;k<IN_DIM;k++){
    float4 w0 = CF4(&Win[k*HID + c0]);
    float4 w1 = CF4(&Win[k*HID + c0 + 256]);
    #pragma unroll
    for (int i=0;i<4;i++){
      float xv = xs[r0+i][k];
      acc[i][0].x = fmaf(xv, w0.x, acc[i][0].x);
      acc[i][0].y = fmaf(xv, w0.y, acc[i][0].y);
      acc[i][0].z = fmaf(xv, w0.z, acc[i][0].z);
      acc[i][0].w = fmaf(xv, w0.w, acc[i][0].w);
      acc[i][1].x = fmaf(xv, w1.x, acc[i][1].x);
      acc[i][1].y = fmaf(xv, w1.y, acc[i][1].y);
      acc[i][1].z = fmaf(xv, w1.z, acc[i][1].z);
      acc[i][1].w = fmaf(xv, w1.w, acc[i][1].w);
    }
  }
  #pragma unroll
  for (int i=0;i<4;i++){
    int m = m0 + r0 + i;
    F4(&h[(size_t)m*HID + c0])       = acc[i][0];
    F4(&h[(size_t)m*HID + c0 + 256]) = acc[i][1];
  }
  #pragma unroll
  for (int i=0;i<4;i++){
    int m = m0 + r0 + i;
    float s_ = (acc[i][0].x+acc[i][0].y)+(acc[i][0].z+acc[i][0].w)
             + (acc[i][1].x+acc[i][1].y)+(acc[i][1].z+acc[i][1].w);
    float q  = (acc[i][0].x*acc[i][0].x + acc[i][0].y*acc[i][0].y)
             + (acc[i][0].z*acc[i][0].z + acc[i][0].w*acc[i][0].w)
             + (acc[i][1].x*acc[i][1].x + acc[i][1].y*acc[i][1].y)
             + (acc[i][1].z*acc[i][1].z + acc[i][1].w*acc[i][1].w);
    #pragma unroll
    for (int off=1; off<64; off<<=1){
      s_ += __shfl_xor(s_, off);
      q  += __shfl_xor(q,  off);
    }
    float mu  = s_*(1.f/HID);
    float var = q*(1.f/HID) - mu*mu;
    float rs  = rsqrtf(fmaxf(var,0.f)+EPS);
    if (lane == 0) stats[m] = make_float2(mu, rs);
    float u = binA[lane];
    #pragma unroll 8
    for (int k=0;k<IN_DIM;k++) u = fmaf(xs[r0+i][k], WA1[k*STATE+lane], u);
    U[(size_t)m*STATE+lane] = fmaf(KTAN, rs*(u - mu*GA0[lane]) + BA0[lane], KTAN);
  }
}

// ---------------------------------------------------------------------------
// U[m][s] = KTAN*( rstd*(h@A' - mu*GA) + BA ) + KTAN   (layers 1..3)
__global__ __launch_bounds__(256) void k_ugemm(const float* __restrict__ h,
    const float2* __restrict__ stats, const float* __restrict__ Ap,
    const float* __restrict__ GA, const float* __restrict__ BA,
    float* __restrict__ U)
{
  __shared__ float hsT[32][132];   // [k][m]  16.9 KB
  __shared__ float Bs[32][68];     // [k][n]   8.7 KB
  int m0 = blockIdx.x * 128;
  int tid = threadIdx.x;
  int tx = tid & 15, ty = tid >> 4;
  int kg = tid & 7,  mg = tid >> 3;
  float acc[8][4] = {};
  for (int kc=0; kc<HID; kc+=32){
    {
      const float* hp = &h[(size_t)(m0 + mg*4)*HID + kc + kg*4];
      float4 v0 = CF4(hp);
      float4 v1 = CF4(hp + HID);
      float4 v2 = CF4(hp + 2*HID);
      float4 v3 = CF4(hp + 3*HID);
      F4(&hsT[kg*4+0][mg*4]) = make_float4(v0.x,v1.x,v2.x,v3.x);
      F4(&hsT[kg*4+1][mg*4]) = make_float4(v0.y,v1.y,v2.y,v3.y);
      F4(&hsT[kg*4+2][mg*4]) = make_float4(v0.z,v1.z,v2.z,v3.z);
      F4(&hsT[kg*4+3][mg*4]) = make_float4(v0.w,v1.w,v2.w,v3.w);
    }
    #pragma unroll
    for (int i=0;i<2;i++){
      int idx = tid + i*256;
      int kr = idx >> 4;
      int c4 = idx & 15;
      F4(&Bs[kr][c4*4]) = CF4(&Ap[(kc+kr)*STATE + c4*4]);
    }
    __syncthreads();
    #pragma unroll 8
    for (int kk=0;kk<32;kk++){
      float4 a0 = CF4(&hsT[kk][ty*8]);
      float4 a1 = CF4(&hsT[kk][ty*8+4]);
      float4 bv = CF4(&Bs[kk][tx*4]);
      float am[8] = {a0.x,a0.y,a0.z,a0.w,a1.x,a1.y,a1.z,a1.w};
      #pragma unroll
      for (int i=0;i<8;i++){
        acc[i][0] = fmaf(am[i], bv.x, acc[i][0]);
        acc[i][1] = fmaf(am[i], bv.y, acc[i][1]);
        acc[i][2] = fmaf(am[i], bv.z, acc[i][2]);
        acc[i][3] = fmaf(am[i], bv.w, acc[i][3]);
      }
    }
    __syncthreads();
  }
  int c0 = tx*4;
  float4 ga = CF4(&GA[c0]);
  float4 ba = CF4(&BA[c0]);
  #pragma unroll
  for (int i=0;i<8;i++){
    int m = m0 + ty*8 + i;
    float2 st = stats[m];
    float4 o;
    o.x = fmaf(KTAN, st.y*(acc[i][0] - st.x*ga.x) + ba.x, KTAN);
    o.y = fmaf(KTAN, st.y*(acc[i][1] - st.x*ga.y) + ba.y, KTAN);
    o.z = fmaf(KTAN, st.y*(acc[i][2] - st.x*ga.z) + ba.z, KTAN);
    o.w = fmaf(KTAN, st.y*(acc[i][3] - st.x*ga.w) + ba.w, KTAN);
    F4(&U[(size_t)m*STATE + c0]) = o;
  }
}

// ---------------------------------------------------------------------------
// Sequential recurrence, 1 wave per batch element, register-resident chain.
// 32-deep global prefetch: all next-chunk loads issue before the compute loop
// (each is a coalesced 256B wave read), so L2/L3 latency hides under the
// ~900cy of chain compute. Stores are fire-and-forget, off the dependent chain.
__global__ __launch_bounds__(64) void k_scan(const float* __restrict__ U,
                                             float* __restrict__ H)
{
  int b = blockIdx.x;
  int s = threadIdx.x;
  const float* Up = U + (size_t)b*SEQ*STATE + s;
  float* Hp = H + (size_t)b*SEQ*STATE + s;
  float r = 0.5f;                      // tanh(0) -> r = 0.5
  float cur[32], nxt[32];
  #pragma unroll
  for (int i=0;i<32;i++) cur[i] = Up[i*STATE];
  for (int t0=0; t0<SEQ; t0+=32){
    bool has_next = (t0+32 < SEQ);
    if (has_next){
      #pragma unroll
      for (int i=0;i<32;i++) nxt[i] = Up[(t0+32+i)*STATE];
    }
    #pragma unroll
    for (int i=0;i<32;i++){
      float e = fast_exp2(fmaf(-2.f*KTAN, r, cur[i]));
      r = fast_rcp(1.f + e);
      Hp[(t0+i)*STATE] = fmaf(-2.f, r, 1.f);
    }
    if (has_next){
      #pragma unroll
      for (int i=0;i<32;i++) cur[i] = nxt[i];
    }
  }
}

// ---------------------------------------------------------------------------
// Y epilogue, in place: h += H@C^T + LN(h)*D; emits next-layer row stats.
__global__ __launch_bounds__(256) void k_yep2(
    float* __restrict__ h, const float* __restrict__ Hg,
    const float* __restrict__ C, const float* __restrict__ Dl,
    const float* __restrict__ gl, const float* __restrict__ bl,
    const float2* __restrict__ stats_in, float2* __restrict__ stats_out)
{
  __shared__ float HshT[STATE][132];  // [s][m0..127]  33.8 KB
  __shared__ float CshT[STATE][68];   // [s][j-chunk]  17.4 KB
  int m0 = blockIdx.x * 128;
  int tid = threadIdx.x;
  int tx = tid & 15, ty = tid >> 4;
  int sg = tid & 15, mgg = tid >> 4;
  #pragma unroll
  for (int p=0;p<2;p++){
    const float* hp = &Hg[(size_t)(m0 + p*64 + mgg*4)*STATE + sg*4];
    float4 v0 = CF4(hp);
    float4 v1 = CF4(hp + STATE);
    float4 v2 = CF4(hp + 2*STATE);
    float4 v3 = CF4(hp + 3*STATE);
    int cb = p*64 + mgg*4;
    F4(&HshT[sg*4+0][cb]) = make_float4(v0.x,v1.x,v2.x,v3.x);
    F4(&HshT[sg*4+1][cb]) = make_float4(v0.y,v1.y,v2.y,v3.y);
    F4(&HshT[sg*4+2][cb]) = make_float4(v0.z,v1.z,v2.z,v3.z);
    F4(&HshT[sg*4+3][cb]) = make_float4(v0.w,v1.w,v2.w,v3.w);
  }
  float2 st[8];
  #pragma unroll
  for (int mi=0;mi<8;mi++) st[mi] = stats_in[m0 + ty*8 + mi];
  float sum[8] = {}, sq[8] = {};
  for (int jc=0; jc<HID; jc+=64){
    {
      const float* cp = &C[(size_t)(jc + mgg*4)*STATE + sg*4];
      float4 v0 = CF4(cp);
      float4 v1 = CF4(cp + STATE);
      float4 v2 = CF4(cp + 2*STATE);
      float4 v3 = CF4(cp + 3*STATE);
      F4(&CshT[sg*4+0][mgg*4]) = make_float4(v0.x,v1.x,v2.x,v3.x);
      F4(&CshT[sg*4+1][mgg*4]) = make_float4(v0.y,v1.y,v2.y,v3.y);
      F4(&CshT[sg*4+2][mgg*4]) = make_float4(v0.z,v1.z,v2.z,v3.z);
      F4(&CshT[sg*4+3][mgg*4]) = make_float4(v0.w,v1.w,v2.w,v3.w);
    }
    __syncthreads();
    float acc[8][4] = {};
    #pragma unroll 8
    for (int s=0;s<STATE;s++){
      float4 a0 = CF4(&HshT[s][ty*8]);
      float4 a1 = CF4(&HshT[s][ty*8+4]);
      float4 bv = CF4(&CshT[s][tx*4]);
      float am[8] = {a0.x,a0.y,a0.z,a0.w,a1.x,a1.y,a1.z,a1.w};
      #pragma unroll
      for (int i=0;i<8;i++){
        acc[i][0] = fmaf(am[i], bv.x, acc[i][0]);
        acc[i][1] = fmaf(am[i], bv.y, acc[i][1]);
        acc[i][2] = fmaf(am[i], bv.z, acc[i][2]);
        acc[i][3] = fmaf(am[i], bv.w, acc[i][3]);
      }
    }
    int j0 = jc + tx*4;
    float4 g4 = CF4(&gl[j0]);
    float4 b4 = CF4(&bl[j0]);
    float4 d4 = CF4(&Dl[j0]);
    #pragma unroll
    for (int mi=0;mi<8;mi++){
      int m = m0 + ty*8 + mi;
      float4 hv = CF4(&h[(size_t)m*HID + j0]);
      float mu = st[mi].x, rs = st[mi].y;
      float4 o;
      o.x = hv.x + acc[mi][0] + fmaf((hv.x - mu)*rs, g4.x, b4.x)*d4.x;
      o.y = hv.y + acc[mi][1] + fmaf((hv.y - mu)*rs, g4.y, b4.y)*d4.y;
      o.z = hv.z + acc[mi][2] + fmaf((hv.z - mu)*rs, g4.z, b4.z)*d4.z;
      o.w = hv.w + acc[mi][3] + fmaf((hv.w - mu)*rs, g4.w, b4.w)*d4.w;
      F4(&h[(size_t)m*HID + j0]) = o;
      sum[mi] += (o.x+o.y)+(o.z+o.w);
      sq[mi]  += (o.x*o.x+o.y*o.y)+(o.z*o.z+o.w*o.w);
    }
    __syncthreads();
  }
  #pragma unroll
  for (int mi=0;mi<8;mi++){
    float s_ = sum[mi], q = sq[mi];
    #pragma unroll
    for (int off=1; off<16; off<<=1){
      s_ += __shfl_xor(s_, off);
      q  += __shfl_xor(q,  off);
    }
    if (tx==0){
      float mu  = s_*(1.f/HID);
      float var = q*(1.f/HID) - mu*mu;
      stats_out[m0 + ty*8 + mi] = make_float2(mu, rsqrtf(fmaxf(var,0.f)+EPS));
    }
  }
}

// ---------------------------------------------------------------------------
__global__ __launch_bounds__(256) void k_head(const float* __restrict__ h,
   const float2* __restrict__ stats, const float* __restrict__ ng, const float* __restrict__ nb,
   const float* __restrict__ W1, const float* __restrict__ b1,
   const float* __restrict__ W2, const float* __restrict__ b2,
   float* __restrict__ out)
{
  int bb = blockIdx.x;
  int m = bb*SEQ + (SEQ-1);
  int tid = threadIdx.x;
  __shared__ float xs[HID];
  __shared__ float red[8];
  float2 st = stats[m];
  #pragma unroll
  for (int i=0;i<2;i++){
    int j = tid + i*256;
    float v = h[(size_t)m*HID + j];
    xs[j] = fmaf((v - st.x)*st.y, ng[j], nb[j]);
  }
  __syncthreads();
  float acc = b1[tid];
  #pragma unroll 8
  for (int j=0;j<HID;j++) acc = fmaf(xs[j], W1[j*(HID/2) + tid], acc);
  float ge = 0.5f*acc*(1.f + erff(acc*0.70710678118654752f));
  float p0 = ge*W2[tid*2+0];
  float p1 = ge*W2[tid*2+1];
  #pragma unroll
  for (int off=32; off; off>>=1){ p0 += __shfl_down(p0, off); p1 += __shfl_down(p1, off); }
  int wid = tid>>6;
  if ((tid&63)==0){ red[wid*2]=p0; red[wid*2+1]=p1; }
  __syncthreads();
  if (tid==0){
    float o0=b2[0], o1=b2[1];
    #pragma unroll
    for (int w=0;w<4;w++){ o0+=red[w*2]; o1+=red[w*2+1]; }
    out[bb*2+0]=o0; out[bb*2+1]=o1;
  }
}

// ---------------------------------------------------------------------------
extern "C" void kernel_launch(void* const* d_in, const int* in_sizes, int n_in,
                              void* d_out, int out_size, void* d_ws, size_t ws_size,
                              hipStream_t stream)
{
  (void)in_sizes; (void)n_in; (void)out_size; (void)ws_size;
  const float* x   = (const float*)d_in[0];
  const float* Win = (const float*)d_in[1];
  const float* bin = (const float*)d_in[2];
  const float* A   = (const float*)d_in[3];
  const float* C   = (const float*)d_in[4];
  const float* Dv  = (const float*)d_in[5];
  const float* lng = (const float*)d_in[6];
  const float* lnb = (const float*)d_in[7];
  const float* ng  = (const float*)d_in[8];
  const float* nb  = (const float*)d_in[9];
  const float* W1  = (const float*)d_in[10];
  const float* b1  = (const float*)d_in[11];
  const float* W2  = (const float*)d_in[12];
  const float* b2  = (const float*)d_in[13];
  float* out = (float*)d_out;
  char* ws = (char*)d_ws;
  float*  hbuf = (float*)(ws + 0);                       // 134,217,728
  float*  Ubuf = (float*)(ws + (size_t)134217728);       //  16,777,216
  float*  Hbuf = (float*)(ws + (size_t)150994944);       //  16,777,216
  float2* st0  = (float2*)(ws + (size_t)167772160);      //     524,288
  float2* st1  = (float2*)(ws + (size_t)168296448);      //     524,288
  float*  Ap   = (float*)(ws + (size_t)168820736);       //     524,288
  float*  GAb  = (float*)(ws + (size_t)169345024);       //       1,024
  float*  BAb  = (float*)(ws + (size_t)169346048);       //       1,024
  float*  WA1b = (float*)(ws + (size_t)169351432);       //       8,192
  float*  binAb= (float*)(ws + (size_t)169359624);       //         256

  hipLaunchKernelGGL(k_prep,  dim3(NLAYERS+33), dim3(256), 0, stream,
      A, lng, lnb, Win, bin, Ap, GAb, BAb, WA1b, binAb);
  hipLaunchKernelGGL(k_input, dim3(NTOK/16), dim3(256), 0, stream,
      x, Win, bin, WA1b, binAb, GAb, BAb, hbuf, Ubuf, st0);
  float2* scur = st0; float2* snxt = st1;
  for (int l=0; l<NLAYERS; ++l){
    if (l > 0){
      hipLaunchKernelGGL(k_ugemm, dim3(NTOK/128), dim3(256), 0, stream,
          hbuf, scur, Ap + l*HID*STATE, GAb + l*STATE, BAb + l*STATE, Ubuf);
    }
    hipLaunchKernelGGL(k_scan,  dim3(BATCH),    dim3(64),  0, stream, Ubuf, Hbuf);
    hipLaunchKernelGGL(k_yep2,  dim3(NTOK/128), dim3(256), 0, stream,
        hbuf, Hbuf, C + l*HID*STATE, Dv + l*HID, lng + l*HID, lnb + l*HID, scur, snxt);
    float2* t = scur; scur = snxt; snxt = t;
  }
  hipLaunchKernelGGL(k_head, dim3(BATCH), dim3(256), 0, stream,
      hbuf, scur, ng, nb, W1, b1, W2, b2, out);
}

// Round 7
// 686.666 us; speedup vs baseline: 2.3110x; 1.1486x over previous
//
#include <hip/hip_runtime.h>

#define BATCH   32
#define SEQ     2048
#define IN_DIM  32
#define HID     512
#define STATE   64
#define NLAYERS 4
#define NTOK    (BATCH*SEQ)          // 65536
#define EPS     1e-5f
#define KTAN    2.8853900817779268f  // 2*log2(e)

#define F4(p)  (*reinterpret_cast<float4*>(p))
#define CF4(p) (*reinterpret_cast<const float4*>(p))

typedef __attribute__((ext_vector_type(8))) short short8v;
typedef __attribute__((ext_vector_type(4))) float f32x4;

__device__ __forceinline__ float fast_exp2(float x){ return __builtin_amdgcn_exp2f(x); }
__device__ __forceinline__ float fast_rcp(float x){ return __builtin_amdgcn_rcpf(x); }
__device__ __forceinline__ short f2bf(float f){           // RNE float->bf16
  unsigned u = __float_as_uint(f);
  unsigned r = (u + 0x7FFF + ((u>>16)&1)) >> 16;
  return (short)r;
}

// ---------------------------------------------------------------------------
// All precompute, 37 blocks x 256 threads. Also emits bf16 copy of C.
__global__ __launch_bounds__(256) void k_prep(
    const float* __restrict__ A, const float* __restrict__ g,
    const float* __restrict__ b, const float* __restrict__ Win,
    const float* __restrict__ bin, const float* __restrict__ C,
    float* __restrict__ Ap, float* __restrict__ GA, float* __restrict__ BA,
    float* __restrict__ WA1, float* __restrict__ binA, short* __restrict__ Cb)
{
  __shared__ float red[4][64], red2[4][64];
  int tid = threadIdx.x;
  int s = tid & 63, part = tid >> 6;
  int blk = blockIdx.x;
  if (blk < NLAYERS){
    int l = blk;
    const float* Al = A + l*HID*STATE;
    const float* Cl = C + l*HID*STATE;
    const float* gl = g + l*HID;
    const float* bl = b + l*HID;
    float ga=0.f, ba=0.f;
    for (int j=part*128; j<(part+1)*128; ++j){
      float a  = Al[j*STATE+s];
      float ap = gl[j]*a;
      Ap[l*HID*STATE + j*STATE + s] = ap;
      Cb[l*HID*STATE + j*STATE + s] = f2bf(Cl[j*STATE+s]);
      ga += ap; ba = fmaf(bl[j], a, ba);
    }
    red[part][s]=ga; red2[part][s]=ba;
    __syncthreads();
    if (tid < 64){
      GA[l*STATE+s] = red[0][s]+red[1][s]+red[2][s]+red[3][s];
      BA[l*STATE+s] = red2[0][s]+red2[1][s]+red2[2][s]+red2[3][s];
    }
  } else {
    int k = blk - NLAYERS;            // 0..32; 32 => binA
    const float* w = (k < 32) ? (Win + k*HID) : bin;
    float acc = 0.f;
    for (int j=part*128; j<(part+1)*128; ++j)
      acc = fmaf(w[j], g[j]*A[j*STATE+s], acc);
    red[part][s] = acc;
    __syncthreads();
    if (tid < 64){
      float v = red[0][s]+red[1][s]+red[2][s]+red[3][s];
      if (k < 32) WA1[k*STATE+s] = v; else binA[s] = v;
    }
  }
}

// ---------------------------------------------------------------------------
// Fused input: h = x@Win + bin; layer-0 LN stats from registers; U_0 closed form.
__global__ __launch_bounds__(256) void k_input(const float* __restrict__ x,
    const float* __restrict__ Win, const float* __restrict__ bin,
    const float* __restrict__ WA1, const float* __restrict__ binA,
    const float* __restrict__ GA0, const float* __restrict__ BA0,
    float* __restrict__ h, float* __restrict__ U, float2* __restrict__ stats)
{
  __shared__ float xs[16][32];
  int m0 = blockIdx.x * 16;
  int tid = threadIdx.x;
  #pragma unroll
  for (int i=0;i<2;i++){
    int idx = tid + i*256;
    xs[idx>>5][idx&31] = x[(m0 + (idx>>5))*IN_DIM + (idx&31)];
  }
  __syncthreads();
  int lane = tid & 63, wv = tid >> 6;
  int c0 = lane*4, r0 = wv*4;
  float4 bv0 = CF4(&bin[c0]);
  float4 bv1 = CF4(&bin[c0+256]);
  float4 acc[4][2];
  #pragma unroll
  for (int i=0;i<4;i++){ acc[i][0]=bv0; acc[i][1]=bv1; }
  #pragma unroll 8
  for (int k=0;k<IN_DIM;k++){
    float4 w0 = CF4(&Win[k*HID + c0]);
    float4 w1 = CF4(&Win[k*HID + c0 + 256]);
    #pragma unroll
    for (int i=0;i<4;i++){
      float xv = xs[r0+i][k];
      acc[i][0].x = fmaf(xv, w0.x, acc[i][0].x);
      acc[i][0].y = fmaf(xv, w0.y, acc[i][0].y);
      acc[i][0].z = fmaf(xv, w0.z, acc[i][0].z);
      acc[i][0].w = fmaf(xv, w0.w, acc[i][0].w);
      acc[i][1].x = fmaf(xv, w1.x, acc[i][1].x);
      acc[i][1].y = fmaf(xv, w1.y, acc[i][1].y);
      acc[i][1].z = fmaf(xv, w1.z, acc[i][1].z);
      acc[i][1].w = fmaf(xv, w1.w, acc[i][1].w);
    }
  }
  #pragma unroll
  for (int i=0;i<4;i++){
    int m = m0 + r0 + i;
    F4(&h[(size_t)m*HID + c0])       = acc[i][0];
    F4(&h[(size_t)m*HID + c0 + 256]) = acc[i][1];
  }
  #pragma unroll
  for (int i=0;i<4;i++){
    int m = m0 + r0 + i;
    float s_ = (acc[i][0].x+acc[i][0].y)+(acc[i][0].z+acc[i][0].w)
             + (acc[i][1].x+acc[i][1].y)+(acc[i][1].z+acc[i][1].w);
    float q  = (acc[i][0].x*acc[i][0].x + acc[i][0].y*acc[i][0].y)
             + (acc[i][0].z*acc[i][0].z + acc[i][0].w*acc[i][0].w)
             + (acc[i][1].x*acc[i][1].x + acc[i][1].y*acc[i][1].y)
             + (acc[i][1].z*acc[i][1].z + acc[i][1].w*acc[i][1].w);
    #pragma unroll
    for (int off=1; off<64; off<<=1){
      s_ += __shfl_xor(s_, off);
      q  += __shfl_xor(q,  off);
    }
    float mu  = s_*(1.f/HID);
    float var = q*(1.f/HID) - mu*mu;
    float rs  = rsqrtf(fmaxf(var,0.f)+EPS);
    if (lane == 0) stats[m] = make_float2(mu, rs);
    float u = binA[lane];
    #pragma unroll 8
    for (int k=0;k<IN_DIM;k++) u = fmaf(xs[r0+i][k], WA1[k*STATE+lane], u);
    U[(size_t)m*STATE+lane] = fmaf(KTAN, rs*(u - mu*GA0[lane]) + BA0[lane], KTAN);
  }
}

// ---------------------------------------------------------------------------
// U[m][s] = KTAN*( rstd*(h@A' - mu*GA) + BA ) + KTAN   (layers 1..3)
// BM=64, BK=64, grid 1024, 256 thr, 4m x 4n microtile. fp32.
__global__ __launch_bounds__(256) void k_ugemm(const float* __restrict__ h,
    const float2* __restrict__ stats, const float* __restrict__ Ap,
    const float* __restrict__ GA, const float* __restrict__ BA,
    float* __restrict__ U)
{
  __shared__ float hsT[64][68];   // [k][m]  17.4 KB
  __shared__ float Bs[64][68];    // [k][n]  17.4 KB
  int m0 = blockIdx.x * 64;
  int tid = threadIdx.x;
  int tx = tid & 15, ty = tid >> 4;
  float acc[4][4] = {};
  for (int kc=0; kc<HID; kc+=64){
    {
      const float* hp = &h[(size_t)(m0 + ty*4)*HID + kc + tx*4];
      float4 v0 = CF4(hp);
      float4 v1 = CF4(hp + HID);
      float4 v2 = CF4(hp + 2*HID);
      float4 v3 = CF4(hp + 3*HID);
      F4(&hsT[tx*4+0][ty*4]) = make_float4(v0.x,v1.x,v2.x,v3.x);
      F4(&hsT[tx*4+1][ty*4]) = make_float4(v0.y,v1.y,v2.y,v3.y);
      F4(&hsT[tx*4+2][ty*4]) = make_float4(v0.z,v1.z,v2.z,v3.z);
      F4(&hsT[tx*4+3][ty*4]) = make_float4(v0.w,v1.w,v2.w,v3.w);
    }
    #pragma unroll
    for (int p=0;p<4;p++){
      int idx = tid + p*256;
      int kr = idx >> 4, c4 = idx & 15;
      F4(&Bs[kr][c4*4]) = CF4(&Ap[(size_t)(kc+kr)*STATE + c4*4]);
    }
    __syncthreads();
    #pragma unroll 8
    for (int kk=0;kk<64;kk++){
      float4 a = CF4(&hsT[kk][ty*4]);
      float4 b = CF4(&Bs[kk][tx*4]);
      acc[0][0]=fmaf(a.x,b.x,acc[0][0]); acc[0][1]=fmaf(a.x,b.y,acc[0][1]);
      acc[0][2]=fmaf(a.x,b.z,acc[0][2]); acc[0][3]=fmaf(a.x,b.w,acc[0][3]);
      acc[1][0]=fmaf(a.y,b.x,acc[1][0]); acc[1][1]=fmaf(a.y,b.y,acc[1][1]);
      acc[1][2]=fmaf(a.y,b.z,acc[1][2]); acc[1][3]=fmaf(a.y,b.w,acc[1][3]);
      acc[2][0]=fmaf(a.z,b.x,acc[2][0]); acc[2][1]=fmaf(a.z,b.y,acc[2][1]);
      acc[2][2]=fmaf(a.z,b.z,acc[2][2]); acc[2][3]=fmaf(a.z,b.w,acc[2][3]);
      acc[3][0]=fmaf(a.w,b.x,acc[3][0]); acc[3][1]=fmaf(a.w,b.y,acc[3][1]);
      acc[3][2]=fmaf(a.w,b.z,acc[3][2]); acc[3][3]=fmaf(a.w,b.w,acc[3][3]);
    }
    __syncthreads();
  }
  int c0 = tx*4;
  float4 ga = CF4(&GA[c0]);
  float4 ba = CF4(&BA[c0]);
  #pragma unroll
  for (int i=0;i<4;i++){
    int m = m0 + ty*4 + i;
    float2 st = stats[m];
    float4 o;
    o.x = fmaf(KTAN, st.y*(acc[i][0] - st.x*ga.x) + ba.x, KTAN);
    o.y = fmaf(KTAN, st.y*(acc[i][1] - st.x*ga.y) + ba.y, KTAN);
    o.z = fmaf(KTAN, st.y*(acc[i][2] - st.x*ga.z) + ba.z, KTAN);
    o.w = fmaf(KTAN, st.y*(acc[i][3] - st.x*ga.w) + ba.w, KTAN);
    F4(&U[(size_t)m*STATE + c0]) = o;
  }
}

// ---------------------------------------------------------------------------
// Sequential recurrence, 1 wave per batch element, register-resident chain.
// 32-deep global prefetch; H written as bf16 (consumed by MFMA yep2).
__global__ __launch_bounds__(64) void k_scan(const float* __restrict__ U,
                                             short* __restrict__ H)
{
  int b = blockIdx.x;
  int s = threadIdx.x;
  const float* Up = U + (size_t)b*SEQ*STATE + s;
  short* Hp = H + (size_t)b*SEQ*STATE + s;
  float r = 0.5f;                      // tanh(0) -> r = 0.5
  float cur[32], nxt[32];
  #pragma unroll
  for (int i=0;i<32;i++) cur[i] = Up[i*STATE];
  for (int t0=0; t0<SEQ; t0+=32){
    bool has_next = (t0+32 < SEQ);
    if (has_next){
      #pragma unroll
      for (int i=0;i<32;i++) nxt[i] = Up[(t0+32+i)*STATE];
    }
    #pragma unroll
    for (int i=0;i<32;i++){
      float e = fast_exp2(fmaf(-2.f*KTAN, r, cur[i]));
      r = fast_rcp(1.f + e);
      Hp[(t0+i)*STATE] = f2bf(fmaf(-2.f, r, 1.f));
    }
    if (has_next){
      #pragma unroll
      for (int i=0;i<32;i++) cur[i] = nxt[i];
    }
  }
}

// ---------------------------------------------------------------------------
// Y epilogue via bf16 MFMA: h += H@C^T + LN(h)*D; emits next-layer row stats.
// BM=64, grid 1024, 4 waves; wave w owns rows w*16..w*16+15.
// MFMA 16x16x32: A=H (row-major, K=64 contiguous), B=C (row-major [col][k]).
// D layout: col=lane&15, row=(lane>>4)*4+reg.
__global__ __launch_bounds__(256) void k_yep2(
    float* __restrict__ h, const short* __restrict__ Hg,
    const short* __restrict__ Cb, const float* __restrict__ Dl,
    const float* __restrict__ gl, const float* __restrict__ bl,
    const float2* __restrict__ stats_in, float2* __restrict__ stats_out)
{
  __shared__ __align__(16) short Hsh[64][72];   // 9.2 KB
  __shared__ __align__(16) short Csh[64][72];   // 9.2 KB
  int m0 = blockIdx.x * 64;
  int tid = threadIdx.x;
  int w = tid >> 6, lane = tid & 63;
  int c = lane & 15, q = lane >> 4;
  // stage H tile (64 rows x 64 bf16), linear copy
  #pragma unroll
  for (int p=0;p<2;p++){
    int idx = tid + p*256;
    int row = idx >> 3, kb = idx & 7;
    *reinterpret_cast<short8v*>(&Hsh[row][kb*8]) =
      *reinterpret_cast<const short8v*>(&Hg[(size_t)(m0+row)*STATE + kb*8]);
  }
  float mu[4], rs[4];
  #pragma unroll
  for (int r=0;r<4;r++){
    float2 s2 = stats_in[m0 + w*16 + q*4 + r];
    mu[r]=s2.x; rs[r]=s2.y;
  }
  float sum[4]={0.f,0.f,0.f,0.f}, sq[4]={0.f,0.f,0.f,0.f};
  __syncthreads();
  short8v a0 = *reinterpret_cast<const short8v*>(&Hsh[w*16 + c][q*8]);
  short8v a1 = *reinterpret_cast<const short8v*>(&Hsh[w*16 + c][32 + q*8]);
  for (int jc=0; jc<HID; jc+=64){
    #pragma unroll
    for (int p=0;p<2;p++){
      int idx = tid + p*256;
      int col = idx >> 3, kb = idx & 7;
      *reinterpret_cast<short8v*>(&Csh[col][kb*8]) =
        *reinterpret_cast<const short8v*>(&Cb[(size_t)(jc+col)*STATE + kb*8]);
    }
    __syncthreads();
    f32x4 acc[4];
    #pragma unroll
    for (int t=0;t<4;t++){
      short8v b0 = *reinterpret_cast<const short8v*>(&Csh[t*16 + c][q*8]);
      short8v b1 = *reinterpret_cast<const short8v*>(&Csh[t*16 + c][32 + q*8]);
      f32x4 a = {0.f,0.f,0.f,0.f};
      a = __builtin_amdgcn_mfma_f32_16x16x32_bf16(a0, b0, a, 0, 0, 0);
      a = __builtin_amdgcn_mfma_f32_16x16x32_bf16(a1, b1, a, 0, 0, 0);
      acc[t] = a;
    }
    #pragma unroll
    for (int t=0;t<4;t++){
      int col = jc + t*16 + c;
      float gj = gl[col], bj = bl[col], dj = Dl[col];
      #pragma unroll
      for (int r=0;r<4;r++){
        int m = m0 + w*16 + q*4 + r;
        float hv = h[(size_t)m*HID + col];
        float o = hv + acc[t][r] + fmaf((hv-mu[r])*rs[r], gj, bj)*dj;
        h[(size_t)m*HID + col] = o;
        sum[r] += o; sq[r] += o*o;
      }
    }
    __syncthreads();
  }
  #pragma unroll
  for (int r=0;r<4;r++){
    float s_ = sum[r], qq = sq[r];
    #pragma unroll
    for (int off=1; off<16; off<<=1){
      s_ += __shfl_xor(s_, off);
      qq += __shfl_xor(qq, off);
    }
    if (c==0){
      float muv = s_*(1.f/HID);
      float var = qq*(1.f/HID) - muv*muv;
      stats_out[m0 + w*16 + q*4 + r] = make_float2(muv, rsqrtf(fmaxf(var,0.f)+EPS));
    }
  }
}

// ---------------------------------------------------------------------------
__global__ __launch_bounds__(256) void k_head(const float* __restrict__ h,
   const float2* __restrict__ stats, const float* __restrict__ ng, const float* __restrict__ nb,
   const float* __restrict__ W1, const float* __restrict__ b1,
   const float* __restrict__ W2, const float* __restrict__ b2,
   float* __restrict__ out)
{
  int bb = blockIdx.x;
  int m = bb*SEQ + (SEQ-1);
  int tid = threadIdx.x;
  __shared__ float xs[HID];
  __shared__ float red[8];
  float2 st = stats[m];
  #pragma unroll
  for (int i=0;i<2;i++){
    int j = tid + i*256;
    float v = h[(size_t)m*HID + j];
    xs[j] = fmaf((v - st.x)*st.y, ng[j], nb[j]);
  }
  __syncthreads();
  float acc = b1[tid];
  #pragma unroll 8
  for (int j=0;j<HID;j++) acc = fmaf(xs[j], W1[j*(HID/2) + tid], acc);
  float ge = 0.5f*acc*(1.f + erff(acc*0.70710678118654752f));
  float p0 = ge*W2[tid*2+0];
  float p1 = ge*W2[tid*2+1];
  #pragma unroll
  for (int off=32; off; off>>=1){ p0 += __shfl_down(p0, off); p1 += __shfl_down(p1, off); }
  int wid = tid>>6;
  if ((tid&63)==0){ red[wid*2]=p0; red[wid*2+1]=p1; }
  __syncthreads();
  if (tid==0){
    float o0=b2[0], o1=b2[1];
    #pragma unroll
    for (int w=0;w<4;w++){ o0+=red[w*2]; o1+=red[w*2+1]; }
    out[bb*2+0]=o0; out[bb*2+1]=o1;
  }
}

// ---------------------------------------------------------------------------
extern "C" void kernel_launch(void* const* d_in, const int* in_sizes, int n_in,
                              void* d_out, int out_size, void* d_ws, size_t ws_size,
                              hipStream_t stream)
{
  (void)in_sizes; (void)n_in; (void)out_size; (void)ws_size;
  const float* x   = (const float*)d_in[0];
  const float* Win = (const float*)d_in[1];
  const float* bin = (const float*)d_in[2];
  const float* A   = (const float*)d_in[3];
  const float* C   = (const float*)d_in[4];
  const float* Dv  = (const float*)d_in[5];
  const float* lng = (const float*)d_in[6];
  const float* lnb = (const float*)d_in[7];
  const float* ng  = (const float*)d_in[8];
  const float* nb  = (const float*)d_in[9];
  const float* W1  = (const float*)d_in[10];
  const float* b1  = (const float*)d_in[11];
  const float* W2  = (const float*)d_in[12];
  const float* b2  = (const float*)d_in[13];
  float* out = (float*)d_out;
  char* ws = (char*)d_ws;
  float*  hbuf = (float*)(ws + 0);                       // 134,217,728
  float*  Ubuf = (float*)(ws + (size_t)134217728);       //  16,777,216
  short*  Hbuf = (short*)(ws + (size_t)150994944);       //   8,388,608 (bf16)
  float2* st0  = (float2*)(ws + (size_t)159383552);      //     524,288
  float2* st1  = (float2*)(ws + (size_t)159907840);      //     524,288
  float*  Ap   = (float*)(ws + (size_t)160432128);       //     524,288
  float*  GAb  = (float*)(ws + (size_t)160956416);       //       1,024
  float*  BAb  = (float*)(ws + (size_t)160957440);       //       1,024
  float*  WA1b = (float*)(ws + (size_t)160958464);       //       8,192
  float*  binAb= (float*)(ws + (size_t)160966656);       //         256
  short*  Cb   = (short*)(ws + (size_t)160966912);       //     262,144 (bf16)

  hipLaunchKernelGGL(k_prep,  dim3(NLAYERS+33), dim3(256), 0, stream,
      A, lng, lnb, Win, bin, C, Ap, GAb, BAb, WA1b, binAb, Cb);
  hipLaunchKernelGGL(k_input, dim3(NTOK/16), dim3(256), 0, stream,
      x, Win, bin, WA1b, binAb, GAb, BAb, hbuf, Ubuf, st0);
  float2* scur = st0; float2* snxt = st1;
  for (int l=0; l<NLAYERS; ++l){
    if (l > 0){
      hipLaunchKernelGGL(k_ugemm, dim3(NTOK/64), dim3(256), 0, stream,
          hbuf, scur, Ap + l*HID*STATE, GAb + l*STATE, BAb + l*STATE, Ubuf);
    }
    hipLaunchKernelGGL(k_scan,  dim3(BATCH),   dim3(64),  0, stream, Ubuf, Hbuf);
    hipLaunchKernelGGL(k_yep2,  dim3(NTOK/64), dim3(256), 0, stream,
        hbuf, Hbuf, Cb + l*HID*STATE, Dv + l*HID, lng + l*HID, lnb + l*HID, scur, snxt);
    float2* t = scur; scur = snxt; snxt = t;
  }
  hipLaunchKernelGGL(k_head, dim3(BATCH), dim3(256), 0, stream,
      hbuf, scur, ng, nb, W1, b1, W2, b2, out);
}

// Round 8
// 482.061 us; speedup vs baseline: 3.2919x; 1.4244x over previous
//
#include <hip/hip_runtime.h>

#define BATCH   32
#define SEQ     2048
#define IN_DIM  32
#define HID     512
#define STATE   64
#define NLAYERS 4
#define NTOK    (BATCH*SEQ)          // 65536
#define EPS     1e-5f
#define KTAN    2.8853900817779268f  // 2*log2(e)

#define F4(p)  (*reinterpret_cast<float4*>(p))
#define CF4(p) (*reinterpret_cast<const float4*>(p))

typedef __attribute__((ext_vector_type(8))) short short8v;
typedef __attribute__((ext_vector_type(4))) short short4v;
typedef __attribute__((ext_vector_type(4))) float f32x4;

__device__ __forceinline__ float fast_exp2(float x){ return __builtin_amdgcn_exp2f(x); }
__device__ __forceinline__ float fast_rcp(float x){ return __builtin_amdgcn_rcpf(x); }
__device__ __forceinline__ short f2bf(float f){           // RNE float->bf16
  unsigned u = __float_as_uint(f);
  unsigned r = (u + 0x7FFF + ((u>>16)&1)) >> 16;
  return (short)r;
}
__device__ __forceinline__ float bf2f(short s){
  return __uint_as_float(((unsigned)(unsigned short)s) << 16);
}

// ---------------------------------------------------------------------------
// All precompute, 37 blocks x 256 threads. Emits bf16 C and bf16 A'^T.
__global__ __launch_bounds__(256) void k_prep(
    const float* __restrict__ A, const float* __restrict__ g,
    const float* __restrict__ b, const float* __restrict__ Win,
    const float* __restrict__ bin, const float* __restrict__ C,
    short* __restrict__ ApT, float* __restrict__ GA, float* __restrict__ BA,
    float* __restrict__ WA1, float* __restrict__ binA, short* __restrict__ Cb)
{
  __shared__ float red[4][64], red2[4][64];
  int tid = threadIdx.x;
  int s = tid & 63, part = tid >> 6;
  int blk = blockIdx.x;
  if (blk < NLAYERS){
    int l = blk;
    const float* Al = A + l*HID*STATE;
    const float* Cl = C + l*HID*STATE;
    const float* gl = g + l*HID;
    const float* bl = b + l*HID;
    float ga=0.f, ba=0.f;
    for (int j=part*128; j<(part+1)*128; ++j){
      float a  = Al[j*STATE+s];
      float ap = gl[j]*a;
      ApT[l*HID*STATE + s*HID + j] = f2bf(ap);      // [s][j] bf16 (MFMA B)
      Cb[l*HID*STATE + j*STATE + s] = f2bf(Cl[j*STATE+s]);
      ga += ap; ba = fmaf(bl[j], a, ba);
    }
    red[part][s]=ga; red2[part][s]=ba;
    __syncthreads();
    if (tid < 64){
      GA[l*STATE+s] = red[0][s]+red[1][s]+red[2][s]+red[3][s];
      BA[l*STATE+s] = red2[0][s]+red2[1][s]+red2[2][s]+red2[3][s];
    }
  } else {
    int k = blk - NLAYERS;            // 0..32; 32 => binA
    const float* w = (k < 32) ? (Win + k*HID) : bin;
    float acc = 0.f;
    for (int j=part*128; j<(part+1)*128; ++j)
      acc = fmaf(w[j], g[j]*A[j*STATE+s], acc);
    red[part][s] = acc;
    __syncthreads();
    if (tid < 64){
      float v = red[0][s]+red[1][s]+red[2][s]+red[3][s];
      if (k < 32) WA1[k*STATE+s] = v; else binA[s] = v;
    }
  }
}

// ---------------------------------------------------------------------------
// Fused input: h(bf16) = x@Win + bin; layer-0 LN stats from fp32 registers;
// U_0 closed form via WA1/binA.
__global__ __launch_bounds__(256) void k_input(const float* __restrict__ x,
    const float* __restrict__ Win, const float* __restrict__ bin,
    const float* __restrict__ WA1, const float* __restrict__ binA,
    const float* __restrict__ GA0, const float* __restrict__ BA0,
    short* __restrict__ h, float* __restrict__ U, float2* __restrict__ stats)
{
  __shared__ float xs[16][32];
  int m0 = blockIdx.x * 16;
  int tid = threadIdx.x;
  #pragma unroll
  for (int i=0;i<2;i++){
    int idx = tid + i*256;
    xs[idx>>5][idx&31] = x[(m0 + (idx>>5))*IN_DIM + (idx&31)];
  }
  __syncthreads();
  int lane = tid & 63, wv = tid >> 6;
  int c0 = lane*4, r0 = wv*4;
  float4 bv0 = CF4(&bin[c0]);
  float4 bv1 = CF4(&bin[c0+256]);
  float4 acc[4][2];
  #pragma unroll
  for (int i=0;i<4;i++){ acc[i][0]=bv0; acc[i][1]=bv1; }
  #pragma unroll 8
  for (int k=0;k<IN_DIM;k++){
    float4 w0 = CF4(&Win[k*HID + c0]);
    float4 w1 = CF4(&Win[k*HID + c0 + 256]);
    #pragma unroll
    for (int i=0;i<4;i++){
      float xv = xs[r0+i][k];
      acc[i][0].x = fmaf(xv, w0.x, acc[i][0].x);
      acc[i][0].y = fmaf(xv, w0.y, acc[i][0].y);
      acc[i][0].z = fmaf(xv, w0.z, acc[i][0].z);
      acc[i][0].w = fmaf(xv, w0.w, acc[i][0].w);
      acc[i][1].x = fmaf(xv, w1.x, acc[i][1].x);
      acc[i][1].y = fmaf(xv, w1.y, acc[i][1].y);
      acc[i][1].z = fmaf(xv, w1.z, acc[i][1].z);
      acc[i][1].w = fmaf(xv, w1.w, acc[i][1].w);
    }
  }
  #pragma unroll
  for (int i=0;i<4;i++){
    int m = m0 + r0 + i;
    short4v p0 = { f2bf(acc[i][0].x), f2bf(acc[i][0].y), f2bf(acc[i][0].z), f2bf(acc[i][0].w) };
    short4v p1 = { f2bf(acc[i][1].x), f2bf(acc[i][1].y), f2bf(acc[i][1].z), f2bf(acc[i][1].w) };
    *reinterpret_cast<short4v*>(&h[(size_t)m*HID + c0])       = p0;
    *reinterpret_cast<short4v*>(&h[(size_t)m*HID + c0 + 256]) = p1;
  }
  #pragma unroll
  for (int i=0;i<4;i++){
    int m = m0 + r0 + i;
    float s_ = (acc[i][0].x+acc[i][0].y)+(acc[i][0].z+acc[i][0].w)
             + (acc[i][1].x+acc[i][1].y)+(acc[i][1].z+acc[i][1].w);
    float q  = (acc[i][0].x*acc[i][0].x + acc[i][0].y*acc[i][0].y)
             + (acc[i][0].z*acc[i][0].z + acc[i][0].w*acc[i][0].w)
             + (acc[i][1].x*acc[i][1].x + acc[i][1].y*acc[i][1].y)
             + (acc[i][1].z*acc[i][1].z + acc[i][1].w*acc[i][1].w);
    #pragma unroll
    for (int off=1; off<64; off<<=1){
      s_ += __shfl_xor(s_, off);
      q  += __shfl_xor(q,  off);
    }
    float mu  = s_*(1.f/HID);
    float var = q*(1.f/HID) - mu*mu;
    float rs  = rsqrtf(fmaxf(var,0.f)+EPS);
    if (lane == 0) stats[m] = make_float2(mu, rs);
    float u = binA[lane];
    #pragma unroll 8
    for (int k=0;k<IN_DIM;k++) u = fmaf(xs[r0+i][k], WA1[k*STATE+lane], u);
    U[(size_t)m*STATE+lane] = fmaf(KTAN, rs*(u - mu*GA0[lane]) + BA0[lane], KTAN);
  }
}

// ---------------------------------------------------------------------------
// U = KTAN*( rstd*(h@A' - mu*GA) + BA ) + KTAN  via bf16 MFMA (layers 1..3).
// BM=64, grid 1024, 4 waves, each wave 16 rows x all 64 s.
// A=h row-major [m][k], B=ApT [s][k]; D: col(s)=lane&15, row=(lane>>4)*4+reg.
__global__ __launch_bounds__(256) void k_ugemm(const short* __restrict__ hb,
    const float2* __restrict__ stats, const short* __restrict__ ApT,
    const float* __restrict__ GA, const float* __restrict__ BA,
    float* __restrict__ U)
{
  __shared__ __align__(16) short Hsh[64][72];   // 9.2 KB
  __shared__ __align__(16) short Bsh[64][72];   // 9.2 KB
  int m0 = blockIdx.x * 64;
  int tid = threadIdx.x;
  int w = tid >> 6, lane = tid & 63;
  int c = lane & 15, q = lane >> 4;
  float mu[4], rs[4];
  #pragma unroll
  for (int r=0;r<4;r++){
    float2 s2 = stats[m0 + w*16 + q*4 + r];
    mu[r]=s2.x; rs[r]=s2.y;
  }
  f32x4 acc[4] = {{0.f,0.f,0.f,0.f},{0.f,0.f,0.f,0.f},{0.f,0.f,0.f,0.f},{0.f,0.f,0.f,0.f}};
  for (int kc=0; kc<HID; kc+=64){
    #pragma unroll
    for (int p=0;p<2;p++){
      int idx = tid + p*256;
      int row = idx >> 3, kb = idx & 7;
      *reinterpret_cast<short8v*>(&Hsh[row][kb*8]) =
        *reinterpret_cast<const short8v*>(&hb[(size_t)(m0+row)*HID + kc + kb*8]);
      *reinterpret_cast<short8v*>(&Bsh[row][kb*8]) =
        *reinterpret_cast<const short8v*>(&ApT[(size_t)row*HID + kc + kb*8]);
    }
    __syncthreads();
    short8v a0 = *reinterpret_cast<const short8v*>(&Hsh[w*16 + c][q*8]);
    short8v a1 = *reinterpret_cast<const short8v*>(&Hsh[w*16 + c][32 + q*8]);
    #pragma unroll
    for (int t=0;t<4;t++){
      short8v b0 = *reinterpret_cast<const short8v*>(&Bsh[t*16 + c][q*8]);
      short8v b1 = *reinterpret_cast<const short8v*>(&Bsh[t*16 + c][32 + q*8]);
      acc[t] = __builtin_amdgcn_mfma_f32_16x16x32_bf16(a0, b0, acc[t], 0, 0, 0);
      acc[t] = __builtin_amdgcn_mfma_f32_16x16x32_bf16(a1, b1, acc[t], 0, 0, 0);
    }
    __syncthreads();
  }
  #pragma unroll
  for (int t=0;t<4;t++){
    int s = t*16 + c;
    float ga = GA[s], ba = BA[s];
    #pragma unroll
    for (int r=0;r<4;r++){
      int m = m0 + w*16 + q*4 + r;
      U[(size_t)m*STATE + s] = fmaf(KTAN, rs[r]*(acc[t][r] - mu[r]*ga) + ba, KTAN);
    }
  }
}

// ---------------------------------------------------------------------------
// Sequential recurrence, 1 wave per batch element, register-resident chain.
// 32-deep global prefetch; H written as bf16.
__global__ __launch_bounds__(64) void k_scan(const float* __restrict__ U,
                                             short* __restrict__ H)
{
  int b = blockIdx.x;
  int s = threadIdx.x;
  const float* Up = U + (size_t)b*SEQ*STATE + s;
  short* Hp = H + (size_t)b*SEQ*STATE + s;
  float r = 0.5f;                      // tanh(0) -> r = 0.5
  float cur[32], nxt[32];
  #pragma unroll
  for (int i=0;i<32;i++) cur[i] = Up[i*STATE];
  for (int t0=0; t0<SEQ; t0+=32){
    bool has_next = (t0+32 < SEQ);
    if (has_next){
      #pragma unroll
      for (int i=0;i<32;i++) nxt[i] = Up[(t0+32+i)*STATE];
    }
    #pragma unroll
    for (int i=0;i<32;i++){
      float e = fast_exp2(fmaf(-2.f*KTAN, r, cur[i]));
      r = fast_rcp(1.f + e);
      Hp[(t0+i)*STATE] = f2bf(fmaf(-2.f, r, 1.f));
    }
    if (has_next){
      #pragma unroll
      for (int i=0;i<32;i++) cur[i] = nxt[i];
    }
  }
}

// ---------------------------------------------------------------------------
// Y epilogue via bf16 MFMA, h(bf16) RMW in place; emits next-layer row stats.
__global__ __launch_bounds__(256) void k_yep2(
    short* __restrict__ h, const short* __restrict__ Hg,
    const short* __restrict__ Cb, const float* __restrict__ Dl,
    const float* __restrict__ gl, const float* __restrict__ bl,
    const float2* __restrict__ stats_in, float2* __restrict__ stats_out)
{
  __shared__ __align__(16) short Hsh[64][72];   // 9.2 KB
  __shared__ __align__(16) short Csh[64][72];   // 9.2 KB
  int m0 = blockIdx.x * 64;
  int tid = threadIdx.x;
  int w = tid >> 6, lane = tid & 63;
  int c = lane & 15, q = lane >> 4;
  #pragma unroll
  for (int p=0;p<2;p++){
    int idx = tid + p*256;
    int row = idx >> 3, kb = idx & 7;
    *reinterpret_cast<short8v*>(&Hsh[row][kb*8]) =
      *reinterpret_cast<const short8v*>(&Hg[(size_t)(m0+row)*STATE + kb*8]);
  }
  float mu[4], rs[4];
  #pragma unroll
  for (int r=0;r<4;r++){
    float2 s2 = stats_in[m0 + w*16 + q*4 + r];
    mu[r]=s2.x; rs[r]=s2.y;
  }
  float sum[4]={0.f,0.f,0.f,0.f}, sq[4]={0.f,0.f,0.f,0.f};
  __syncthreads();
  short8v a0 = *reinterpret_cast<const short8v*>(&Hsh[w*16 + c][q*8]);
  short8v a1 = *reinterpret_cast<const short8v*>(&Hsh[w*16 + c][32 + q*8]);
  for (int jc=0; jc<HID; jc+=64){
    #pragma unroll
    for (int p=0;p<2;p++){
      int idx = tid + p*256;
      int col = idx >> 3, kb = idx & 7;
      *reinterpret_cast<short8v*>(&Csh[col][kb*8]) =
        *reinterpret_cast<const short8v*>(&Cb[(size_t)(jc+col)*STATE + kb*8]);
    }
    __syncthreads();
    f32x4 acc[4];
    #pragma unroll
    for (int t=0;t<4;t++){
      short8v b0 = *reinterpret_cast<const short8v*>(&Csh[t*16 + c][q*8]);
      short8v b1 = *reinterpret_cast<const short8v*>(&Csh[t*16 + c][32 + q*8]);
      f32x4 a = {0.f,0.f,0.f,0.f};
      a = __builtin_amdgcn_mfma_f32_16x16x32_bf16(a0, b0, a, 0, 0, 0);
      a = __builtin_amdgcn_mfma_f32_16x16x32_bf16(a1, b1, a, 0, 0, 0);
      acc[t] = a;
    }
    #pragma unroll
    for (int t=0;t<4;t++){
      int col = jc + t*16 + c;
      float gj = gl[col], bj = bl[col], dj = Dl[col];
      #pragma unroll
      for (int r=0;r<4;r++){
        int m = m0 + w*16 + q*4 + r;
        float hv = bf2f(h[(size_t)m*HID + col]);
        float o = hv + acc[t][r] + fmaf((hv-mu[r])*rs[r], gj, bj)*dj;
        h[(size_t)m*HID + col] = f2bf(o);
        sum[r] += o; sq[r] += o*o;
      }
    }
    __syncthreads();
  }
  #pragma unroll
  for (int r=0;r<4;r++){
    float s_ = sum[r], qq = sq[r];
    #pragma unroll
    for (int off=1; off<16; off<<=1){
      s_ += __shfl_xor(s_, off);
      qq += __shfl_xor(qq, off);
    }
    if (c==0){
      float muv = s_*(1.f/HID);
      float var = qq*(1.f/HID) - muv*muv;
      stats_out[m0 + w*16 + q*4 + r] = make_float2(muv, rsqrtf(fmaxf(var,0.f)+EPS));
    }
  }
}

// ---------------------------------------------------------------------------
__global__ __launch_bounds__(256) void k_head(const short* __restrict__ h,
   const float2* __restrict__ stats, const float* __restrict__ ng, const float* __restrict__ nb,
   const float* __restrict__ W1, const float* __restrict__ b1,
   const float* __restrict__ W2, const float* __restrict__ b2,
   float* __restrict__ out)
{
  int bb = blockIdx.x;
  int m = bb*SEQ + (SEQ-1);
  int tid = threadIdx.x;
  __shared__ float xs[HID];
  __shared__ float red[8];
  float2 st = stats[m];
  #pragma unroll
  for (int i=0;i<2;i++){
    int j = tid + i*256;
    float v = bf2f(h[(size_t)m*HID + j]);
    xs[j] = fmaf((v - st.x)*st.y, ng[j], nb[j]);
  }
  __syncthreads();
  float acc = b1[tid];
  #pragma unroll 8
  for (int j=0;j<HID;j++) acc = fmaf(xs[j], W1[j*(HID/2) + tid], acc);
  float ge = 0.5f*acc*(1.f + erff(acc*0.70710678118654752f));
  float p0 = ge*W2[tid*2+0];
  float p1 = ge*W2[tid*2+1];
  #pragma unroll
  for (int off=32; off; off>>=1){ p0 += __shfl_down(p0, off); p1 += __shfl_down(p1, off); }
  int wid = tid>>6;
  if ((tid&63)==0){ red[wid*2]=p0; red[wid*2+1]=p1; }
  __syncthreads();
  if (tid==0){
    float o0=b2[0], o1=b2[1];
    #pragma unroll
    for (int w=0;w<4;w++){ o0+=red[w*2]; o1+=red[w*2+1]; }
    out[bb*2+0]=o0; out[bb*2+1]=o1;
  }
}

// ---------------------------------------------------------------------------
extern "C" void kernel_launch(void* const* d_in, const int* in_sizes, int n_in,
                              void* d_out, int out_size, void* d_ws, size_t ws_size,
                              hipStream_t stream)
{
  (void)in_sizes; (void)n_in; (void)out_size; (void)ws_size;
  const float* x   = (const float*)d_in[0];
  const float* Win = (const float*)d_in[1];
  const float* bin = (const float*)d_in[2];
  const float* A   = (const float*)d_in[3];
  const float* C   = (const float*)d_in[4];
  const float* Dv  = (const float*)d_in[5];
  const float* lng = (const float*)d_in[6];
  const float* lnb = (const float*)d_in[7];
  const float* ng  = (const float*)d_in[8];
  const float* nb  = (const float*)d_in[9];
  const float* W1  = (const float*)d_in[10];
  const float* b1  = (const float*)d_in[11];
  const float* W2  = (const float*)d_in[12];
  const float* b2  = (const float*)d_in[13];
  float* out = (float*)d_out;
  char* ws = (char*)d_ws;
  short*  hb   = (short*)(ws + 0);                       //  67,108,864 (bf16)
  float*  Ubuf = (float*)(ws + (size_t)67108864);        //  16,777,216
  short*  Hbuf = (short*)(ws + (size_t)83886080);        //   8,388,608 (bf16)
  float2* st0  = (float2*)(ws + (size_t)92274688);       //     524,288
  float2* st1  = (float2*)(ws + (size_t)92798976);       //     524,288
  short*  ApT  = (short*)(ws + (size_t)93323264);        //     262,144 (bf16)
  float*  GAb  = (float*)(ws + (size_t)93585408);        //       1,024
  float*  BAb  = (float*)(ws + (size_t)93586432);        //       1,024
  float*  WA1b = (float*)(ws + (size_t)93587456);        //       8,192
  float*  binAb= (float*)(ws + (size_t)93595648);        //         256
  short*  Cb   = (short*)(ws + (size_t)93595904);        //     262,144 (bf16)

  hipLaunchKernelGGL(k_prep,  dim3(NLAYERS+33), dim3(256), 0, stream,
      A, lng, lnb, Win, bin, C, ApT, GAb, BAb, WA1b, binAb, Cb);
  hipLaunchKernelGGL(k_input, dim3(NTOK/16), dim3(256), 0, stream,
      x, Win, bin, WA1b, binAb, GAb, BAb, hb, Ubuf, st0);
  float2* scur = st0; float2* snxt = st1;
  for (int l=0; l<NLAYERS; ++l){
    if (l > 0){
      hipLaunchKernelGGL(k_ugemm, dim3(NTOK/64), dim3(256), 0, stream,
          hb, scur, ApT + l*HID*STATE, GAb + l*STATE, BAb + l*STATE, Ubuf);
    }
    hipLaunchKernelGGL(k_scan,  dim3(BATCH),   dim3(64),  0, stream, Ubuf, Hbuf);
    hipLaunchKernelGGL(k_yep2,  dim3(NTOK/64), dim3(256), 0, stream,
        hb, Hbuf, Cb + l*HID*STATE, Dv + l*HID, lng + l*HID, lnb + l*HID, scur, snxt);
    float2* t = scur; scur = snxt; snxt = t;
  }
  hipLaunchKernelGGL(k_head, dim3(BATCH), dim3(256), 0, stream,
      hb, scur, ng, nb, W1, b1, W2, b2, out);
}